// Round 14
// baseline (531.179 us; speedup 1.0000x reference)
//
#include <hip/hip_runtime.h>
#include <cstddef>
#include <cstdint>

// B=8, C=2, Hf=257, T=2048, D_IN=514, DM=256, NL=4, N=32
// Activations: fp32 planes (b, 2*DM=512, T). GEMMs run bf16 MFMA.
// R14: decoder split into 2 co-resident blocks per (t-tile,b) (m-halves of
// 5/4 x 128-row chunks) -- R13's grid was exactly 1 block/CU so the stage/
// K-loop/store phases had nothing to overlap with (Occupancy 18.9%,
// MfmaUtil 14%). 2 blocks/CU restores phase-level TLP; z staged 2x (L2-warm).

typedef __attribute__((ext_vector_type(8))) short short8;
typedef __attribute__((ext_vector_type(4))) float float4v;

__device__ __forceinline__ unsigned short f2bf(float f) {
    union { float f; unsigned u; } v; v.f = f;
    const unsigned r = v.u + 0x7fffu + ((v.u >> 16) & 1u);  // RNE
    return (unsigned short)(r >> 16);
}

__device__ __forceinline__ float gelu_tanh(float x) {
    const float x3 = x * x * x;
    const float v  = 0.7978845608028654f * (x + 0.044715f * x3);
    const float e  = __expf(2.f * v);
    const float th = 1.f - 2.f / (e + 1.f);
    return 0.5f * x * (1.f + th);
}

// packed bf16 pair: dst.lo = bf16(lo), dst.hi = bf16(hi) (RNE)
__device__ __forceinline__ unsigned cvt_pk_bf16(float lo, float hi) {
    unsigned r;
    asm("v_cvt_pk_bf16_f32 %0, %1, %2" : "=v"(r) : "v"(lo), "v"(hi));
    return r;
}
// unpack bf16x2 dword -> float2 (exact)
__device__ __forceinline__ float2 unpk(unsigned d) {
    float2 u;
    u.x = __uint_as_float(d << 16);
    u.y = __uint_as_float(d & 0xffff0000u);
    return u;
}

// packed complex mul-add: w (*) p + u via 2x v_pk_fma_f32
__device__ __forceinline__ float2 cfma(const float2 w, const float2 p,
                                       const float2 u) {
    float2 t, r;
    asm("v_pk_fma_f32 %0, %1, %2, %3 op_sel:[1,1,0] op_sel_hi:[1,0,1] neg_lo:[1,0,0] neg_hi:[0,0,0]"
        : "=v"(t) : "v"(w), "v"(p), "v"(u));
    asm("v_pk_fma_f32 %0, %1, %2, %3 op_sel:[0,0,0] op_sel_hi:[0,1,1]"
        : "=v"(r) : "v"(w), "v"(p), "v"(t));
    return r;
}

#define ASYNC_COPY16(gp, lp) __builtin_amdgcn_global_load_lds( \
    (const __attribute__((address_space(1))) unsigned int*)(gp), \
    (__attribute__((address_space(3))) unsigned int*)(lp), 16, 0, 0)

// ---------- ONE builder launch for all weights/biases ----------
__global__ __launch_bounds__(256) void buildall_k(
    const float* __restrict__ enc_Wr, const float* __restrict__ enc_Wi,
    const float* __restrict__ out_Wr, const float* __restrict__ out_Wi,
    const float* __restrict__ dec_Wr, const float* __restrict__ dec_Wi,
    const float* __restrict__ enc_br, const float* __restrict__ enc_bi,
    const float* __restrict__ out_br, const float* __restrict__ out_bi,
    const float* __restrict__ dec_br, const float* __restrict__ dec_bi,
    unsigned short* __restrict__ A_enc, unsigned short* __restrict__ A_lay,
    unsigned short* __restrict__ A_dec,
    float* __restrict__ b_enc, float* __restrict__ b_lay,
    float* __restrict__ b_dec)
{
    int blk = blockIdx.x;
    const int tid = threadIdx.x;
    if (blk < 2112) {
        const int i = blk * 256 + tid;
        const int m = i / 1056, k = i - m * 1056;
        const int ri = m >= 256, g = m & 255;
        const int blk2 = k >= 528;
        const int hh = k - blk2 * 528;
        float val = 0.f;
        if (hh < 514) {
            const float wr = enc_Wr[(size_t)g * 514 + hh];
            const float wi = enc_Wi[(size_t)g * 514 + hh];
            val = ri ? (blk2 ? wr : wi) : (blk2 ? -wi : wr);
        }
        A_enc[i] = f2bf(val);
        return;
    }
    blk -= 2112;
    if (blk < 4096) {
        const int l = blk >> 10;
        const int i = ((blk & 1023) << 8) + tid;
        const float* Wr = out_Wr + (size_t)l * 65536;
        const float* Wi = out_Wi + (size_t)l * 65536;
        const int m = i >> 9, k = i & 511;
        const int ri = m >= 256, g = m & 255;
        const int blk2 = k >> 8, hh = k & 255;
        const float wr = Wr[(size_t)g * 256 + hh];
        const float wi = Wi[(size_t)g * 256 + hh];
        A_lay[(size_t)l * 262144 + i] =
            f2bf(ri ? (blk2 ? wr : wi) : (blk2 ? -wi : wr));
        return;
    }
    blk -= 4096;
    if (blk < 2304) {
        // decoder W, INTERLEAVED rows: m' -> (g = m'>>1, comp = m'&1).
        const int i = blk * 256 + tid;
        const int m = i >> 9, k = i & 511;
        const int g = m >> 1, comp = m & 1;
        float val = 0.f;
        if (g < 514) {
            const int blk2 = k >> 8, hh = k & 255;
            const float wr = dec_Wr[(size_t)g * 256 + hh];
            const float wi = dec_Wi[(size_t)g * 256 + hh];
            val = comp ? (blk2 ? wr : wi) : (blk2 ? -wi : wr);
        }
        A_dec[i] = f2bf(val);
        return;
    }
    blk -= 2304;
    if (blk < 2) {
        const int i = blk * 256 + tid;
        b_enc[i] = (i < 256) ? enc_br[i] : enc_bi[i - 256];
        return;
    }
    blk -= 2;
    if (blk < 8) {
        const int l = blk >> 1;
        const int i = ((blk & 1) << 8) + tid;
        b_lay[l * 512 + i] = (i < 256) ? out_br[l * 256 + i]
                                       : out_bi[l * 256 + i - 256];
        return;
    }
    blk -= 8;
    {
        const int i = blk * 256 + tid;
        if (i < 1028) b_dec[i] = (i & 1) ? dec_bi[i >> 1] : dec_br[i >> 1];
    }
}

// ---------- per-layer scan-matrix builder: P / TriG / M per h ----------
// Pmat layout: [h][3][64*64] bf16, rows/cols interleaved re/im:
// entry(2a+ri, 2b+ci) of complex coef v: ri=0:(Re,-Im) ri=1:(Im,Re).
__global__ __launch_bounds__(256) void buildmm_k(
    const float* __restrict__ log_dt, const float* __restrict__ log_A_real,
    const float* __restrict__ A_imag, const float* __restrict__ C_r,
    const float* __restrict__ C_i, unsigned short* __restrict__ Pmat, int l)
{
    const int h = blockIdx.x;
    const int tid = threadIdx.x;
    __shared__ float2 pw[32][33];
    __shared__ float2 csh[32], gsh[32];

    if (tid < 32) {
        const size_t pidx = ((size_t)l * 256 + h) * 32 + tid;
        const float dt = __expf(log_dt[l * 256 + h]);
        const float Ar = -__expf(log_A_real[pidx]);
        const float Ai = A_imag[pidx];
        const float er = __expf(Ar * dt);
        float sv, cv;
        __sincosf(Ai * dt, &sv, &cv);
        const float wr = er * cv, wi = er * sv;
        const float den = 1.f / (Ar * Ar + Ai * Ai);
        const float nr = wr - 1.f, ni = wi;
        const float qr = (nr * Ar + ni * Ai) * den;
        const float qi = (ni * Ar - nr * Ai) * den;
        const float cr = C_r[pidx], ci = C_i[pidx];
        csh[tid] = make_float2(cr * qr - ci * qi, cr * qi + ci * qr);
        float2 p = make_float2(1.f, 0.f);
        const float2 w = make_float2(wr, wi);
#pragma unroll 1
        for (int k = 0; k < 33; ++k) {
            pw[tid][k] = p;
            const float pr = p.x * w.x - p.y * w.y;
            p.y = p.x * w.y + p.y * w.x;
            p.x = pr;
        }
    }
    __syncthreads();
    if (tid < 32) {
        float2 g = make_float2(0.f, 0.f);
#pragma unroll 1
        for (int n = 0; n < 32; ++n) {
            const float2 c = csh[n], p = pw[n][tid];
            g.x += c.x * p.x - c.y * p.y;
            g.y += c.x * p.y + c.y * p.x;
        }
        gsh[tid] = g;
    }
    __syncthreads();

    unsigned short* base = Pmat + (size_t)h * 12288;
    const int row = tid >> 2, cq = (tid & 3) * 16;
    const int half = row & 1, src = row >> 1;
#pragma unroll 1
    for (int c = cq; c < cq + 16; ++c) {
        const int ci = c & 1, idx = c >> 1;
        const float2 v = pw[src][31 - idx];
        base[row * 64 + c] = f2bf(half ? (ci ? v.x : v.y) : (ci ? -v.y : v.x));
        const float2 g = (idx <= src) ? gsh[src - idx] : make_float2(0.f, 0.f);
        base[4096 + row * 64 + c] = f2bf(half ? (ci ? g.x : g.y) : (ci ? -g.y : g.x));
        const float2 wp = pw[idx][src + 1];
        const float2 cc = csh[idx];
        const float2 e = make_float2(cc.x * wp.x - cc.y * wp.y,
                                     cc.x * wp.y + cc.y * wp.x);
        base[8192 + row * 64 + c] = f2bf(half ? (ci ? e.x : e.y) : (ci ? -e.y : e.x));
    }
}

// ---------- encoder input pack: x (b,514,T,2) fp32 -> xp (b,T,1056) bf16 ----------
__global__ __launch_bounds__(256) void packx_k(const float* __restrict__ x,
                                               unsigned short* __restrict__ xp)
{
    const int t0 = blockIdx.x * 64, d0 = blockIdx.y * 64, b = blockIdx.z;
    __shared__ unsigned short tr_[64][72];
    __shared__ unsigned short ti_[64][72];
    const int tid = threadIdx.x;
    const int tp = tid & 31, dl0 = tid >> 5;
#pragma unroll
    for (int p = 0; p < 8; ++p) {
        const int d = dl0 + p * 8;
        const int gd = d0 + d;
        float4 v = make_float4(0.f, 0.f, 0.f, 0.f);
        if (gd < 514) v = *(const float4*)(x + (((size_t)b * 514 + gd) * 2048 + t0 + tp * 2) * 2);
        tr_[tp * 2 + 0][d] = f2bf(v.x); ti_[tp * 2 + 0][d] = f2bf(v.y);
        tr_[tp * 2 + 1][d] = f2bf(v.z); ti_[tp * 2 + 1][d] = f2bf(v.w);
    }
    __syncthreads();
    const int dc = tid & 7;
    const int kloc = d0 + dc * 8;
    if (kloc < 528) {
#pragma unroll
        for (int p = 0; p < 2; ++p) {
            const int t = (tid >> 3) + p * 32;
            const size_t rowb = ((size_t)b * 2048 + t0 + t) * 1056;
            *(short8*)&xp[rowb + kloc]       = *(const short8*)&tr_[t][dc * 8];
            *(short8*)&xp[rowb + 528 + kloc] = *(const short8*)&ti_[t][dc * 8];
        }
    }
}

// ---------- bf16 MFMA GEMM (encoder): out(b,M,T) = A * Bm^T + bias ----------
__global__ __launch_bounds__(256, 2) void mgemm_k(
    const unsigned short* __restrict__ A, const float* __restrict__ bias,
    const unsigned short* __restrict__ Bm, float* __restrict__ out,
    int M, int Kp)
{
    __shared__ unsigned short As[4096];  // [m 0..127][k 0..31]
    __shared__ unsigned short Bs[4096];  // [t 0..127][k 0..31]
    const int tid = threadIdx.x;
    const int w = tid >> 6, lane = tid & 63;
    const int m0 = blockIdx.x * 128, t0 = blockIdx.y * 128, b = blockIdx.z;
    const int wm = w & 1, wn = w >> 1;

    const unsigned short* Ab = A + (size_t)m0 * Kp;
    const unsigned short* Bb = Bm + ((size_t)b * 2048 + t0) * Kp;

    const int c0 = w * 64 + lane;
    const int r0 = c0 >> 2, q0 = (c0 & 3) * 8;
    const int c1 = c0 + 256;
    const int r1 = c1 >> 2, q1 = (c1 & 3) * 8;
    unsigned short* As0 = &As[(size_t)(w * 64) * 8];
    unsigned short* As1 = &As[(size_t)(w * 64 + 256) * 8];
    unsigned short* Bs0 = &Bs[(size_t)(w * 64) * 8];
    unsigned short* Bs1 = &Bs[(size_t)(w * 64 + 256) * 8];

    float4v acc[4][4];
#pragma unroll
    for (int i = 0; i < 4; ++i)
#pragma unroll
        for (int j = 0; j < 4; ++j) acc[i][j] = (float4v){0.f, 0.f, 0.f, 0.f};

    const int arow = wm * 64 + (lane & 15);
    const int brow = wn * 64 + (lane & 15);
    const int kq = (lane >> 4) * 8;

    for (int k0 = 0; k0 < Kp; k0 += 32) {
        ASYNC_COPY16(Ab + (size_t)r0 * Kp + k0 + q0, As0);
        ASYNC_COPY16(Ab + (size_t)r1 * Kp + k0 + q1, As1);
        ASYNC_COPY16(Bb + (size_t)r0 * Kp + k0 + q0, Bs0);
        ASYNC_COPY16(Bb + (size_t)r1 * Kp + k0 + q1, Bs1);
        __syncthreads();
        short8 af[4], bf[4];
#pragma unroll
        for (int i = 0; i < 4; ++i) af[i] = *(const short8*)&As[(arow + i * 16) * 32 + kq];
#pragma unroll
        for (int j = 0; j < 4; ++j) bf[j] = *(const short8*)&Bs[(brow + j * 16) * 32 + kq];
#pragma unroll
        for (int i = 0; i < 4; ++i)
#pragma unroll
            for (int j = 0; j < 4; ++j)
                acc[i][j] = __builtin_amdgcn_mfma_f32_16x16x32_bf16(af[i], bf[j], acc[i][j], 0, 0, 0);
        __syncthreads();
    }

    const int col = lane & 15;
    const int rq = (lane >> 4) * 4;
#pragma unroll
    for (int i = 0; i < 4; ++i) {
        const int mloc = wm * 64 + i * 16 + rq;
#pragma unroll
        for (int r = 0; r < 4; ++r) {
            const int m = m0 + mloc + r;
            const float bs = bias[m];
#pragma unroll
            for (int j = 0; j < 4; ++j) {
                const int t = t0 + wn * 64 + j * 16 + col;
                out[((size_t)b * 512 + m) * 2048 + t] = acc[i][j][r] + bs;
            }
        }
    }
}

// ---------- fused layer GEMM + residual + channel LayerNorm ----------
// R7 verified optimum: 64-t tile, B staged directly from t-major y planes
// (transpose on the LDS write), XOR swizzle mask(t) = ((t&7)^((t>>3)&7))<<4.
__global__ __launch_bounds__(512, 2) void mgemmln_k(
    const unsigned short* __restrict__ A, const float* __restrict__ bias,
    const unsigned short* __restrict__ Bm, float* __restrict__ z,
    const float* __restrict__ gamr, const float* __restrict__ gami,
    const float* __restrict__ betr, const float* __restrict__ beti, int l)
{
    __shared__ unsigned short Bs[64][512];   // 64KB, swizzled
    __shared__ float biasS[512], gamS[512], betS[512];
    __shared__ float sred[8][64][2];
    __shared__ float sstat[2][64][2];
    const int tid = threadIdx.x;
    const int w = tid >> 6, lane = tid & 63;
    const int t0g = blockIdx.x * 64, b = blockIdx.y;
    unsigned char* BsB = (unsigned char*)&Bs[0][0];

    // ---- stage B from y planes, transpose-on-write ----
    {
        const unsigned short* ysrc = Bm + (size_t)b * 512 * 2048 + t0g;
        const int tseg = lane & 7;       // 8-t segment (t = tseg*8 + j)
        const int rloc = lane >> 3;      // row within the wave's octet
#pragma unroll
        for (int p = 0; p < 8; ++p) {
            const int krow = w * 8 + rloc + p * 64;
            const short8 v = *(const short8*)(ysrc + (size_t)krow * 2048 + tseg * 8);
#pragma unroll
            for (int j = 0; j < 8; ++j) {
                const int t = tseg * 8 + j;
                const int mask = (((t & 7) ^ ((t >> 3) & 7)) << 4);
                *(unsigned short*)(BsB + t * 1024 + ((krow * 2) ^ mask)) =
                    ((const unsigned short*)&v)[j];
            }
        }
        const int m = tid, g = m & 255, comp = m >> 8;
        biasS[m] = bias[m];
        gamS[m] = (comp ? gami : gamr)[l * 256 + g];
        betS[m] = (comp ? beti : betr)[l * 256 + g];
    }
    __syncthreads();

    // ---- K-loop: A direct from global (L2-resident), B from LDS ----
    float4v acc[4][4];
#pragma unroll
    for (int i = 0; i < 4; ++i)
#pragma unroll
        for (int j = 0; j < 4; ++j) acc[i][j] = (float4v){0.f, 0.f, 0.f, 0.f};

    const int brow = lane & 15;
    const int kq8 = (lane >> 4) * 8;
    const unsigned short* Ab = A + ((size_t)(w * 64 + brow)) * 512 + kq8;
    int baseB[4], maskB[4];
#pragma unroll
    for (int j = 0; j < 4; ++j) {
        const int t = j * 16 + brow;
        baseB[j] = t * 1024;
        maskB[j] = (((t & 7) ^ ((t >> 3) & 7)) << 4);
    }

#define LOADF(af_, bf_, k0_) do {                                              \
    _Pragma("unroll")                                                          \
    for (int i = 0; i < 4; ++i)                                                \
        af_[i] = *(const short8*)(Ab + (size_t)i * 16 * 512 + (k0_));          \
    _Pragma("unroll")                                                          \
    for (int j = 0; j < 4; ++j)                                                \
        bf_[j] = *(const short8*)(BsB + baseB[j] + ((((k0_) + kq8) * 2) ^ maskB[j])); \
} while (0)
#define MFMAS(af_, bf_) do {                                                   \
    _Pragma("unroll")                                                          \
    for (int i = 0; i < 4; ++i)                                                \
        _Pragma("unroll")                                                      \
        for (int j = 0; j < 4; ++j)                                            \
            acc[i][j] = __builtin_amdgcn_mfma_f32_16x16x32_bf16(af_[i], bf_[j], acc[i][j], 0, 0, 0); \
} while (0)

    {
        short8 afA[4], bfA[4], afB[4], bfB[4];
        LOADF(afA, bfA, 0);
#pragma unroll 1
        for (int kk = 0; kk < 16; kk += 2) {
            LOADF(afB, bfB, kk * 32 + 32);
            MFMAS(afA, bfA);
            if (kk + 2 < 16) LOADF(afA, bfA, kk * 32 + 64);
            MFMAS(afB, bfB);
        }
    }
#undef LOADF
#undef MFMAS

    // ---- epilogue: v = acc + bias + z_old, LN stats, normalize, write z ----
    const int q4 = (lane >> 4) * 4;
    float4 b4[4], g4[4], e4[4];
#pragma unroll
    for (int i = 0; i < 4; ++i) {
        const int m0 = w * 64 + i * 16 + q4;
        b4[i] = *(const float4*)&biasS[m0];
        g4[i] = *(const float4*)&gamS[m0];
        e4[i] = *(const float4*)&betS[m0];
    }

    float s1[4], s2[4];
#pragma unroll
    for (int j = 0; j < 4; ++j) { s1[j] = 0.f; s2[j] = 0.f; }
#pragma unroll
    for (int j = 0; j < 4; ++j) {
        const int t = t0g + j * 16 + brow;
#pragma unroll
        for (int i = 0; i < 4; ++i) {
            const int m = w * 64 + i * 16 + q4;
            const float* zp = &z[((size_t)b * 512 + m) * 2048 + t];
            const float bb[4] = {b4[i].x, b4[i].y, b4[i].z, b4[i].w};
#pragma unroll
            for (int r = 0; r < 4; ++r) {
                const float v = acc[i][j][r] + bb[r] + zp[(size_t)r * 2048];
                acc[i][j][r] = v;
                s1[j] += v; s2[j] += v * v;
            }
        }
    }
#pragma unroll
    for (int j = 0; j < 4; ++j) {
        s1[j] += __shfl_xor(s1[j], 16); s2[j] += __shfl_xor(s2[j], 16);
        s1[j] += __shfl_xor(s1[j], 32); s2[j] += __shfl_xor(s2[j], 32);
    }
    if (lane < 16) {
#pragma unroll
        for (int j = 0; j < 4; ++j) {
            sred[w][j * 16 + lane][0] = s1[j];
            sred[w][j * 16 + lane][1] = s2[j];
        }
    }
    __syncthreads();
    if (tid < 128) {
        const int t = tid & 63, comp = tid >> 6;
        float S1 = 0.f, S2 = 0.f;
#pragma unroll
        for (int w2 = 0; w2 < 4; ++w2) {
            S1 += sred[comp * 4 + w2][t][0];
            S2 += sred[comp * 4 + w2][t][1];
        }
        const float mn = S1 * (1.f / 256.f);
        const float var = S2 * (1.f / 256.f) - mn * mn;
        sstat[comp][t][0] = mn;
        sstat[comp][t][1] = rsqrtf(var + 1e-5f);
    }
    __syncthreads();
    const int comp = w >> 2;
#pragma unroll
    for (int j = 0; j < 4; ++j) {
        const int tl = j * 16 + brow;
        const float mn = sstat[comp][tl][0], rs = sstat[comp][tl][1];
        const int t = t0g + tl;
#pragma unroll
        for (int i = 0; i < 4; ++i) {
            const int m = w * 64 + i * 16 + q4;
            float* zp = &z[((size_t)b * 512 + m) * 2048 + t];
            const float gg[4] = {g4[i].x, g4[i].y, g4[i].z, g4[i].w};
            const float ee[4] = {e4[i].x, e4[i].y, e4[i].z, e4[i].w};
#pragma unroll
            for (int r = 0; r < 4; ++r)
                zp[(size_t)r * 2048] = (acc[i][j][r] - mn) * rs * gg[r] + ee[r];
        }
    }
}

// ---------- fused decoder: transpose+convert z in-stage, GEMM, paired out ----------
// R14: grid (2, 32, 8) -- 2 co-resident blocks per (t-tile,b). Block bx
// loops over 128-row m-chunks (bx=0: chunks 0..4, bx=1: 5..8; 9x128=1152).
// z staged once per block (2x total, L2-warm). A rows interleaved
// (m' -> g=m'>>1, comp=m'&1) -> float2 {re,im} full-line stores (R7).
__global__ __launch_bounds__(512, 2) void mgemmdec_k(
    const unsigned short* __restrict__ A, const float* __restrict__ bias,
    const float* __restrict__ z, float* __restrict__ out)
{
    __shared__ unsigned short Bs[64][512];   // 64KB, swizzled
    const int tid = threadIdx.x;
    const int w = tid >> 6, lane = tid & 63;
    const int bx = blockIdx.x;
    const int t0g = blockIdx.y * 64, b = blockIdx.z;
    unsigned char* BsB = (unsigned char*)&Bs[0][0];

    // ---- stage B from z fp32 planes: f2bf + transpose-on-write ----
    {
        const float* zsrc = z + (size_t)b * 512 * 2048 + t0g;
        const int tseg = lane & 7, rloc = lane >> 3;
#pragma unroll
        for (int p = 0; p < 8; ++p) {
            const int krow = w * 8 + rloc + p * 64;
            const float* rowp = zsrc + (size_t)krow * 2048 + tseg * 8;
            const float4 va = *(const float4*)rowp;
            const float4 vb = *(const float4*)(rowp + 4);
            const float vals[8] = {va.x, va.y, va.z, va.w, vb.x, vb.y, vb.z, vb.w};
#pragma unroll
            for (int j = 0; j < 8; ++j) {
                const int t = tseg * 8 + j;
                const int mask = (((t & 7) ^ ((t >> 3) & 7)) << 4);
                *(unsigned short*)(BsB + t * 1024 + ((krow * 2) ^ mask)) = f2bf(vals[j]);
            }
        }
    }
    __syncthreads();

    const int brow = lane & 15;
    const int kq8 = (lane >> 4) * 8;
    int baseB[4], maskB[4];
#pragma unroll
    for (int j = 0; j < 4; ++j) {
        const int t = j * 16 + brow;
        baseB[j] = t * 1024;
        maskB[j] = (((t & 7) ^ ((t >> 3) & 7)) << 4);
    }

#define LOADF(af_, bf_, k0_) do {                                              \
    af_ = *(const short8*)(Ab + (k0_));                                        \
    _Pragma("unroll")                                                          \
    for (int j = 0; j < 4; ++j)                                                \
        bf_[j] = *(const short8*)(BsB + baseB[j] + ((((k0_) + kq8) * 2) ^ maskB[j])); \
} while (0)
#define MFMAS(af_, bf_) do {                                                   \
    _Pragma("unroll")                                                          \
    for (int j = 0; j < 4; ++j)                                                \
        acc[j] = __builtin_amdgcn_mfma_f32_16x16x32_bf16(af_, bf_[j], acc[j], 0, 0, 0); \
} while (0)

    const int cbeg = bx * 5, cend = bx ? 9 : 5;
#pragma unroll 1
    for (int mc = cbeg; mc < cend; ++mc) {
        const int m0b = mc * 128;
        const unsigned short* Ab = A + ((size_t)(m0b + w * 16 + brow)) * 512 + kq8;

        float4v acc[4];
#pragma unroll
        for (int j = 0; j < 4; ++j) acc[j] = (float4v){0.f, 0.f, 0.f, 0.f};

        {
            short8 afA, bfA[4], afB, bfB[4];
            LOADF(afA, bfA, 0);
#pragma unroll 1
            for (int kk = 0; kk < 16; kk += 2) {
                LOADF(afB, bfB, kk * 32 + 32);
                MFMAS(afA, bfA);
                if (kk + 2 < 16) LOADF(afA, bfA, kk * 32 + 64);
                MFMAS(afB, bfB);
            }
        }

        // ---- epilogue: bias + paired float2 stores (g<514 guard) ----
        const int q4 = (lane >> 4) * 4;
        const int mb = m0b + w * 16 + q4;            // even
#pragma unroll
        for (int pr = 0; pr < 2; ++pr) {
            const int m2 = mb + pr * 2;              // even row of the pair
            const int g = m2 >> 1;
            if (g >= 514) continue;
            const float br = bias[m2], bi2 = bias[m2 + 1];
            float* op = out + (((size_t)b * 514 + g) * 2048 + t0g) * 2;
#pragma unroll
            for (int j = 0; j < 4; ++j) {
                const int tl = j * 16 + brow;
                const float2 v = make_float2(acc[j][pr * 2 + 0] + br,
                                             acc[j][pr * 2 + 1] + bi2);
                *(float2*)(op + (size_t)tl * 2) = v;
            }
        }
    }
#undef LOADF
#undef MFMAS
}

// ---------- MFMA S4D scan: A=PxU, butterfly states, Y=TriGxU+MxS ----------
// R12 (verified): block per (b,h), U bf16-pair staged, A-agg = PxU via MFMA,
// fp32 butterfly over 64 chunk-aggregates, S split hi+lo bf16,
// Y = TriGxU + MxS_hi + MxS_lo via MFMA.
__global__ __launch_bounds__(256) void s4mm_k(
    const float* __restrict__ z, unsigned short* __restrict__ y,
    const unsigned short* __restrict__ Pmat,
    const float* __restrict__ log_dt, const float* __restrict__ log_A_real,
    const float* __restrict__ A_imag, const float* __restrict__ Dsk, int l)
{
    const int h = blockIdx.x, b = blockIdx.y;
    const int tid = threadIdx.x;
    const int lane = tid & 63, wv = tid >> 6;
    __shared__ float2 wsh[32];
    __shared__ float dsh;
    __shared__ unsigned Ub[64][36];    // u bf16 pairs
    __shared__ unsigned Sb[64][36];    // state hi
    __shared__ unsigned Sc[64][36];    // state lo (residual)
    __shared__ float2 scr[64][33];     // A-agg, then Y

    if (tid < 32) {
        const size_t pidx = ((size_t)l * 256 + h) * 32 + tid;
        const float dt = __expf(log_dt[l * 256 + h]);
        const float Ar = -__expf(log_A_real[pidx]);
        const float Ai = A_imag[pidx];
        const float er = __expf(Ar * dt);
        float sv, cv;
        __sincosf(Ai * dt, &sv, &cv);
        wsh[tid] = make_float2(er * cv, er * sv);
    }
    if (tid == 32) dsh = Dsk[l * 256 + h];

    // ---- stage U: thread owns t = tid*8..+8 = chunk c0q, j0q..+8 ----
    const int c0q = tid >> 2, j0q = (tid & 3) * 8;
    {
        const float* zrp = z + ((size_t)b * 512 + h) * 2048 + tid * 8;
        const float* zip = zrp + 256 * 2048;
        const float4 r0 = *(const float4*)zrp, r1 = *(const float4*)(zrp + 4);
        const float4 i0 = *(const float4*)zip, i1 = *(const float4*)(zip + 4);
        uint4 pa, pb;
        pa.x = cvt_pk_bf16(r0.x, i0.x); pa.y = cvt_pk_bf16(r0.y, i0.y);
        pa.z = cvt_pk_bf16(r0.z, i0.z); pa.w = cvt_pk_bf16(r0.w, i0.w);
        pb.x = cvt_pk_bf16(r1.x, i1.x); pb.y = cvt_pk_bf16(r1.y, i1.y);
        pb.z = cvt_pk_bf16(r1.z, i1.z); pb.w = cvt_pk_bf16(r1.w, i1.w);
        *(uint4*)&Ub[c0q][j0q]     = pa;
        *(uint4*)&Ub[c0q][j0q + 4] = pb;
    }
    __syncthreads();

    const unsigned short* Pg = Pmat + (size_t)h * 12288;
    const int bcol = lane & 15, kq = (lane >> 4) * 8;
    const int arow = (wv * 16 + bcol) * 64 + kq;
    const float2 zero2 = make_float2(0.f, 0.f);

    // ---- matmul1: A-agg = P x U ----
    {
        float4v a1[4];
#pragma unroll
        for (int jf = 0; jf < 4; ++jf) a1[jf] = (float4v){0.f, 0.f, 0.f, 0.f};
#pragma unroll
        for (int k0 = 0; k0 < 64; k0 += 32) {
            const short8 af = *(const short8*)(Pg + arow + k0);
#pragma unroll
            for (int jf = 0; jf < 4; ++jf) {
                const short8 bf = *(const short8*)&Ub[16 * jf + bcol][(k0 + kq) >> 1];
                a1[jf] = __builtin_amdgcn_mfma_f32_16x16x32_bf16(af, bf, a1[jf], 0, 0, 0);
            }
        }
        const int mode0 = (wv * 16 + (lane >> 4) * 4) >> 1;
#pragma unroll
        for (int jf = 0; jf < 4; ++jf) {
            const int c = 16 * jf + bcol;
            scr[c][mode0]     = make_float2(a1[jf][0], a1[jf][1]);
            scr[c][mode0 + 1] = make_float2(a1[jf][2], a1[jf][3]);
        }
    }
    __syncthreads();

    // ---- butterfly scan over 64 chunk-aggregates; wave wv owns 8 modes ----
    {
        const int dstc = (lane + 1) & 63;
#pragma unroll 1
        for (int jm = 0; jm < 8; ++jm) {
            const int n = wv * 8 + jm;
            const float2 wm = wsh[n];
            float2 f = wm;
#pragma unroll
            for (int s = 0; s < 5; ++s) f = cfma(f, f, zero2);   // w^32
            float2 qv = scr[lane][n], pq = f;
#pragma unroll
            for (int s = 0; s < 6; ++s) {
                const int d = 1 << s;
                float2 sh;
                sh.x = __shfl_up(qv.x, (unsigned)d);
                sh.y = __shfl_up(qv.y, (unsigned)d);
                const float2 qn = cfma(pq, sh, qv);
                if (lane >= d) qv = qn;
                pq = cfma(pq, pq, zero2);
            }
            // exclusive via store-to-lane+1; split hi/lo bf16
            const unsigned hi = cvt_pk_bf16(qv.x, qv.y);
            const float2 hv = unpk(hi);
            const unsigned lo = cvt_pk_bf16(qv.x - hv.x, qv.y - hv.y);
            Sb[dstc][n] = (lane == 63) ? 0u : hi;
            Sc[dstc][n] = (lane == 63) ? 0u : lo;
        }
    }
    __syncthreads();

    // ---- matmul2+3: Y = TriG x U + M x S_hi + M x S_lo ----
    {
        const unsigned short* Tg = Pg + 4096;
        const unsigned short* Mg = Pg + 8192;
        float4v a2[4];
#pragma unroll
        for (int jf = 0; jf < 4; ++jf) a2[jf] = (float4v){0.f, 0.f, 0.f, 0.f};
#pragma unroll
        for (int k0 = 0; k0 < 64; k0 += 32) {
            const short8 af = *(const short8*)(Tg + arow + k0);
#pragma unroll
            for (int jf = 0; jf < 4; ++jf) {
                const short8 bf = *(const short8*)&Ub[16 * jf + bcol][(k0 + kq) >> 1];
                a2[jf] = __builtin_amdgcn_mfma_f32_16x16x32_bf16(af, bf, a2[jf], 0, 0, 0);
            }
        }
#pragma unroll
        for (int k0 = 0; k0 < 64; k0 += 32) {
            const short8 af = *(const short8*)(Mg + arow + k0);
#pragma unroll
            for (int jf = 0; jf < 4; ++jf) {
                const short8 bf = *(const short8*)&Sb[16 * jf + bcol][(k0 + kq) >> 1];
                a2[jf] = __builtin_amdgcn_mfma_f32_16x16x32_bf16(af, bf, a2[jf], 0, 0, 0);
            }
        }
#pragma unroll
        for (int k0 = 0; k0 < 64; k0 += 32) {
            const short8 af = *(const short8*)(Mg + arow + k0);
#pragma unroll
            for (int jf = 0; jf < 4; ++jf) {
                const short8 bf = *(const short8*)&Sc[16 * jf + bcol][(k0 + kq) >> 1];
                a2[jf] = __builtin_amdgcn_mfma_f32_16x16x32_bf16(af, bf, a2[jf], 0, 0, 0);
            }
        }
        __syncthreads();   // scr (A-agg) fully consumed; reuse as Y
        const int jp0 = (wv * 16 + (lane >> 4) * 4) >> 1;
#pragma unroll
        for (int jf = 0; jf < 4; ++jf) {
            const int c = 16 * jf + bcol;
            scr[c][jp0]     = make_float2(a2[jf][0], a2[jf][1]);
            scr[c][jp0 + 1] = make_float2(a2[jf][2], a2[jf][3]);
        }
    }
    __syncthreads();

    // ---- final: D-skip + gelu + bf16 pack + coalesced stores ----
    {
        const float dv = dsh;
        unsigned short* yrp = y + ((size_t)b * 512 + h) * 2048 + tid * 8;
        unsigned short* yip = yrp + 256 * 2048;
        short8 vr8, vi8;
#pragma unroll
        for (int j = 0; j < 8; ++j) {
            const float2 yv = scr[c0q][j0q + j];
            const float2 uv = unpk(Ub[c0q][j0q + j]);
            ((unsigned short*)&vr8)[j] = f2bf(gelu_tanh(__builtin_fmaf(dv, uv.x, yv.x)));
            ((unsigned short*)&vi8)[j] = f2bf(gelu_tanh(__builtin_fmaf(dv, uv.y, yv.y)));
        }
        *(short8*)yrp = vr8;
        *(short8*)yip = vi8;
    }
}

extern "C" void kernel_launch(void* const* d_in, const int* in_sizes, int n_in,
                              void* d_out, int out_size, void* d_ws, size_t ws_size,
                              hipStream_t stream)
{
    const float* x        = (const float*)d_in[0];
    const float* enc_Wr   = (const float*)d_in[1];
    const float* enc_Wi   = (const float*)d_in[2];
    const float* enc_br   = (const float*)d_in[3];
    const float* enc_bi   = (const float*)d_in[4];
    const float* log_dt   = (const float*)d_in[5];
    const float* log_A_r  = (const float*)d_in[6];
    const float* A_imag   = (const float*)d_in[7];
    const float* C_r      = (const float*)d_in[8];
    const float* C_i      = (const float*)d_in[9];
    const float* Dp       = (const float*)d_in[10];
    const float* out_Wr   = (const float*)d_in[11];
    const float* out_Wi   = (const float*)d_in[12];
    const float* out_br   = (const float*)d_in[13];
    const float* out_bi   = (const float*)d_in[14];
    const float* ln_gr    = (const float*)d_in[15];
    const float* ln_gi    = (const float*)d_in[16];
    const float* ln_br    = (const float*)d_in[17];
    const float* ln_bi    = (const float*)d_in[18];
    const float* dec_Wr   = (const float*)d_in[19];
    const float* dec_Wi   = (const float*)d_in[20];
    const float* dec_br   = (const float*)d_in[21];
    const float* dec_bi   = (const float*)d_in[22];

    // ---- workspace layout (bytes) ----
    uint8_t* W = (uint8_t*)d_ws;
    float* z             = (float*)W;                       // 33,554,432
    unsigned short* Pmat = (unsigned short*)(W + 33554432); // 256x3x4096x2 = 6,291,456 (rebuilt per layer)
    unsigned short* A_enc= (unsigned short*)(W + 50331648); // 512x1056x2  = 1,081,344
    unsigned short* A_lay= (unsigned short*)(W + 51412992); // 4x512x512x2 = 2,097,152
    unsigned short* A_dec= (unsigned short*)(W + 53510144); // 1152x512x2  = 1,179,648
    float* b_enc         = (float*)(W + 54689792);          // 512 f
    float* b_lay         = (float*)(W + 54691840);          // 2048 f
    float* b_dec         = (float*)(W + 54700032);          // 1028 f

    // ---- d_out doubles as scratch ----
    unsigned short* y   = (unsigned short*)((uint8_t*)d_out + 33554432);   // 16,777,216
    unsigned short* xp  = (unsigned short*)d_out;  // 34,603,008; dead after encoder GEMM

    // ---- build all weights/biases in one launch ----
    buildall_k<<<8527, 256, 0, stream>>>(enc_Wr, enc_Wi, out_Wr, out_Wi,
                                         dec_Wr, dec_Wi, enc_br, enc_bi,
                                         out_br, out_bi, dec_br, dec_bi,
                                         A_enc, A_lay, A_dec,
                                         b_enc, b_lay, b_dec);

    // ---- encoder: pack x -> xp, GEMM -> z ----
    packx_k<<<dim3(32, 9, 8), 256, 0, stream>>>(x, xp);
    mgemm_k<<<dim3(4, 16, 8), 256, 0, stream>>>(A_enc, b_enc, xp, z, 512, 1056);

    // ---- layers: scan-matrices -> MFMA scan -> fused GEMM+residual+LN ----
    for (int l = 0; l < 4; ++l) {
        buildmm_k<<<256, 256, 0, stream>>>(log_dt, log_A_r, A_imag, C_r, C_i, Pmat, l);
        s4mm_k<<<dim3(256, 8), 256, 0, stream>>>(z, y, Pmat, log_dt, log_A_r,
                                                 A_imag, Dp, l);
        mgemmln_k<<<dim3(32, 8), 512, 0, stream>>>(A_lay + (size_t)l * 262144,
                                                   b_lay + l * 512, y, z,
                                                   ln_gr, ln_gi, ln_br, ln_bi, l);
    }

    // ---- decoder: 2 co-resident m-half blocks per t-tile -> d_out ----
    mgemmdec_k<<<dim3(2, 32, 8), 512, 0, stream>>>(A_dec, b_dec, z, (float*)d_out);
}

// Round 15
// 524.039 us; speedup vs baseline: 1.0136x; 1.0136x over previous
//
#include <hip/hip_runtime.h>
#include <cstddef>
#include <cstdint>

// B=8, C=2, Hf=257, T=2048, D_IN=514, DM=256, NL=4, N=32
// Activations: fp32 planes (b, 2*DM=512, T). GEMMs run bf16 MFMA.
// R15: revert decoder to R13 (verified 50us): single block per (t-tile,b),
// 3x384-row m-chunks with acc[3][4] (3 MFMAs amortize each LDS B-read).
// R14's 2-block/128-row split regressed (B-read amortization 3->1, LDS
// conflicts 3x) -- amortization beats co-residency for this kernel.

typedef __attribute__((ext_vector_type(8))) short short8;
typedef __attribute__((ext_vector_type(4))) float float4v;

__device__ __forceinline__ unsigned short f2bf(float f) {
    union { float f; unsigned u; } v; v.f = f;
    const unsigned r = v.u + 0x7fffu + ((v.u >> 16) & 1u);  // RNE
    return (unsigned short)(r >> 16);
}

__device__ __forceinline__ float gelu_tanh(float x) {
    const float x3 = x * x * x;
    const float v  = 0.7978845608028654f * (x + 0.044715f * x3);
    const float e  = __expf(2.f * v);
    const float th = 1.f - 2.f / (e + 1.f);
    return 0.5f * x * (1.f + th);
}

// packed bf16 pair: dst.lo = bf16(lo), dst.hi = bf16(hi) (RNE)
__device__ __forceinline__ unsigned cvt_pk_bf16(float lo, float hi) {
    unsigned r;
    asm("v_cvt_pk_bf16_f32 %0, %1, %2" : "=v"(r) : "v"(lo), "v"(hi));
    return r;
}
// unpack bf16x2 dword -> float2 (exact)
__device__ __forceinline__ float2 unpk(unsigned d) {
    float2 u;
    u.x = __uint_as_float(d << 16);
    u.y = __uint_as_float(d & 0xffff0000u);
    return u;
}

// packed complex mul-add: w (*) p + u via 2x v_pk_fma_f32
__device__ __forceinline__ float2 cfma(const float2 w, const float2 p,
                                       const float2 u) {
    float2 t, r;
    asm("v_pk_fma_f32 %0, %1, %2, %3 op_sel:[1,1,0] op_sel_hi:[1,0,1] neg_lo:[1,0,0] neg_hi:[0,0,0]"
        : "=v"(t) : "v"(w), "v"(p), "v"(u));
    asm("v_pk_fma_f32 %0, %1, %2, %3 op_sel:[0,0,0] op_sel_hi:[0,1,1]"
        : "=v"(r) : "v"(w), "v"(p), "v"(t));
    return r;
}

#define ASYNC_COPY16(gp, lp) __builtin_amdgcn_global_load_lds( \
    (const __attribute__((address_space(1))) unsigned int*)(gp), \
    (__attribute__((address_space(3))) unsigned int*)(lp), 16, 0, 0)

// ---------- ONE builder launch for all weights/biases ----------
__global__ __launch_bounds__(256) void buildall_k(
    const float* __restrict__ enc_Wr, const float* __restrict__ enc_Wi,
    const float* __restrict__ out_Wr, const float* __restrict__ out_Wi,
    const float* __restrict__ dec_Wr, const float* __restrict__ dec_Wi,
    const float* __restrict__ enc_br, const float* __restrict__ enc_bi,
    const float* __restrict__ out_br, const float* __restrict__ out_bi,
    const float* __restrict__ dec_br, const float* __restrict__ dec_bi,
    unsigned short* __restrict__ A_enc, unsigned short* __restrict__ A_lay,
    unsigned short* __restrict__ A_dec,
    float* __restrict__ b_enc, float* __restrict__ b_lay,
    float* __restrict__ b_dec)
{
    int blk = blockIdx.x;
    const int tid = threadIdx.x;
    if (blk < 2112) {
        const int i = blk * 256 + tid;
        const int m = i / 1056, k = i - m * 1056;
        const int ri = m >= 256, g = m & 255;
        const int blk2 = k >= 528;
        const int hh = k - blk2 * 528;
        float val = 0.f;
        if (hh < 514) {
            const float wr = enc_Wr[(size_t)g * 514 + hh];
            const float wi = enc_Wi[(size_t)g * 514 + hh];
            val = ri ? (blk2 ? wr : wi) : (blk2 ? -wi : wr);
        }
        A_enc[i] = f2bf(val);
        return;
    }
    blk -= 2112;
    if (blk < 4096) {
        const int l = blk >> 10;
        const int i = ((blk & 1023) << 8) + tid;
        const float* Wr = out_Wr + (size_t)l * 65536;
        const float* Wi = out_Wi + (size_t)l * 65536;
        const int m = i >> 9, k = i & 511;
        const int ri = m >= 256, g = m & 255;
        const int blk2 = k >> 8, hh = k & 255;
        const float wr = Wr[(size_t)g * 256 + hh];
        const float wi = Wi[(size_t)g * 256 + hh];
        A_lay[(size_t)l * 262144 + i] =
            f2bf(ri ? (blk2 ? wr : wi) : (blk2 ? -wi : wr));
        return;
    }
    blk -= 4096;
    if (blk < 2304) {
        // decoder W, INTERLEAVED rows: m' -> (g = m'>>1, comp = m'&1).
        const int i = blk * 256 + tid;
        const int m = i >> 9, k = i & 511;
        const int g = m >> 1, comp = m & 1;
        float val = 0.f;
        if (g < 514) {
            const int blk2 = k >> 8, hh = k & 255;
            const float wr = dec_Wr[(size_t)g * 256 + hh];
            const float wi = dec_Wi[(size_t)g * 256 + hh];
            val = comp ? (blk2 ? wr : wi) : (blk2 ? -wi : wr);
        }
        A_dec[i] = f2bf(val);
        return;
    }
    blk -= 2304;
    if (blk < 2) {
        const int i = blk * 256 + tid;
        b_enc[i] = (i < 256) ? enc_br[i] : enc_bi[i - 256];
        return;
    }
    blk -= 2;
    if (blk < 8) {
        const int l = blk >> 1;
        const int i = ((blk & 1) << 8) + tid;
        b_lay[l * 512 + i] = (i < 256) ? out_br[l * 256 + i]
                                       : out_bi[l * 256 + i - 256];
        return;
    }
    blk -= 8;
    {
        const int i = blk * 256 + tid;
        if (i < 1028) b_dec[i] = (i & 1) ? dec_bi[i >> 1] : dec_br[i >> 1];
    }
}

// ---------- per-layer scan-matrix builder: P / TriG / M per h ----------
// Pmat layout: [h][3][64*64] bf16, rows/cols interleaved re/im:
// entry(2a+ri, 2b+ci) of complex coef v: ri=0:(Re,-Im) ri=1:(Im,Re).
__global__ __launch_bounds__(256) void buildmm_k(
    const float* __restrict__ log_dt, const float* __restrict__ log_A_real,
    const float* __restrict__ A_imag, const float* __restrict__ C_r,
    const float* __restrict__ C_i, unsigned short* __restrict__ Pmat, int l)
{
    const int h = blockIdx.x;
    const int tid = threadIdx.x;
    __shared__ float2 pw[32][33];
    __shared__ float2 csh[32], gsh[32];

    if (tid < 32) {
        const size_t pidx = ((size_t)l * 256 + h) * 32 + tid;
        const float dt = __expf(log_dt[l * 256 + h]);
        const float Ar = -__expf(log_A_real[pidx]);
        const float Ai = A_imag[pidx];
        const float er = __expf(Ar * dt);
        float sv, cv;
        __sincosf(Ai * dt, &sv, &cv);
        const float wr = er * cv, wi = er * sv;
        const float den = 1.f / (Ar * Ar + Ai * Ai);
        const float nr = wr - 1.f, ni = wi;
        const float qr = (nr * Ar + ni * Ai) * den;
        const float qi = (ni * Ar - nr * Ai) * den;
        const float cr = C_r[pidx], ci = C_i[pidx];
        csh[tid] = make_float2(cr * qr - ci * qi, cr * qi + ci * qr);
        float2 p = make_float2(1.f, 0.f);
        const float2 w = make_float2(wr, wi);
#pragma unroll 1
        for (int k = 0; k < 33; ++k) {
            pw[tid][k] = p;
            const float pr = p.x * w.x - p.y * w.y;
            p.y = p.x * w.y + p.y * w.x;
            p.x = pr;
        }
    }
    __syncthreads();
    if (tid < 32) {
        float2 g = make_float2(0.f, 0.f);
#pragma unroll 1
        for (int n = 0; n < 32; ++n) {
            const float2 c = csh[n], p = pw[n][tid];
            g.x += c.x * p.x - c.y * p.y;
            g.y += c.x * p.y + c.y * p.x;
        }
        gsh[tid] = g;
    }
    __syncthreads();

    unsigned short* base = Pmat + (size_t)h * 12288;
    const int row = tid >> 2, cq = (tid & 3) * 16;
    const int half = row & 1, src = row >> 1;
#pragma unroll 1
    for (int c = cq; c < cq + 16; ++c) {
        const int ci = c & 1, idx = c >> 1;
        const float2 v = pw[src][31 - idx];
        base[row * 64 + c] = f2bf(half ? (ci ? v.x : v.y) : (ci ? -v.y : v.x));
        const float2 g = (idx <= src) ? gsh[src - idx] : make_float2(0.f, 0.f);
        base[4096 + row * 64 + c] = f2bf(half ? (ci ? g.x : g.y) : (ci ? -g.y : g.x));
        const float2 wp = pw[idx][src + 1];
        const float2 cc = csh[idx];
        const float2 e = make_float2(cc.x * wp.x - cc.y * wp.y,
                                     cc.x * wp.y + cc.y * wp.x);
        base[8192 + row * 64 + c] = f2bf(half ? (ci ? e.x : e.y) : (ci ? -e.y : e.x));
    }
}

// ---------- encoder input pack: x (b,514,T,2) fp32 -> xp (b,T,1056) bf16 ----------
__global__ __launch_bounds__(256) void packx_k(const float* __restrict__ x,
                                               unsigned short* __restrict__ xp)
{
    const int t0 = blockIdx.x * 64, d0 = blockIdx.y * 64, b = blockIdx.z;
    __shared__ unsigned short tr_[64][72];
    __shared__ unsigned short ti_[64][72];
    const int tid = threadIdx.x;
    const int tp = tid & 31, dl0 = tid >> 5;
#pragma unroll
    for (int p = 0; p < 8; ++p) {
        const int d = dl0 + p * 8;
        const int gd = d0 + d;
        float4 v = make_float4(0.f, 0.f, 0.f, 0.f);
        if (gd < 514) v = *(const float4*)(x + (((size_t)b * 514 + gd) * 2048 + t0 + tp * 2) * 2);
        tr_[tp * 2 + 0][d] = f2bf(v.x); ti_[tp * 2 + 0][d] = f2bf(v.y);
        tr_[tp * 2 + 1][d] = f2bf(v.z); ti_[tp * 2 + 1][d] = f2bf(v.w);
    }
    __syncthreads();
    const int dc = tid & 7;
    const int kloc = d0 + dc * 8;
    if (kloc < 528) {
#pragma unroll
        for (int p = 0; p < 2; ++p) {
            const int t = (tid >> 3) + p * 32;
            const size_t rowb = ((size_t)b * 2048 + t0 + t) * 1056;
            *(short8*)&xp[rowb + kloc]       = *(const short8*)&tr_[t][dc * 8];
            *(short8*)&xp[rowb + 528 + kloc] = *(const short8*)&ti_[t][dc * 8];
        }
    }
}

// ---------- bf16 MFMA GEMM (encoder): out(b,M,T) = A * Bm^T + bias ----------
__global__ __launch_bounds__(256, 2) void mgemm_k(
    const unsigned short* __restrict__ A, const float* __restrict__ bias,
    const unsigned short* __restrict__ Bm, float* __restrict__ out,
    int M, int Kp)
{
    __shared__ unsigned short As[4096];  // [m 0..127][k 0..31]
    __shared__ unsigned short Bs[4096];  // [t 0..127][k 0..31]
    const int tid = threadIdx.x;
    const int w = tid >> 6, lane = tid & 63;
    const int m0 = blockIdx.x * 128, t0 = blockIdx.y * 128, b = blockIdx.z;
    const int wm = w & 1, wn = w >> 1;

    const unsigned short* Ab = A + (size_t)m0 * Kp;
    const unsigned short* Bb = Bm + ((size_t)b * 2048 + t0) * Kp;

    const int c0 = w * 64 + lane;
    const int r0 = c0 >> 2, q0 = (c0 & 3) * 8;
    const int c1 = c0 + 256;
    const int r1 = c1 >> 2, q1 = (c1 & 3) * 8;
    unsigned short* As0 = &As[(size_t)(w * 64) * 8];
    unsigned short* As1 = &As[(size_t)(w * 64 + 256) * 8];
    unsigned short* Bs0 = &Bs[(size_t)(w * 64) * 8];
    unsigned short* Bs1 = &Bs[(size_t)(w * 64 + 256) * 8];

    float4v acc[4][4];
#pragma unroll
    for (int i = 0; i < 4; ++i)
#pragma unroll
        for (int j = 0; j < 4; ++j) acc[i][j] = (float4v){0.f, 0.f, 0.f, 0.f};

    const int arow = wm * 64 + (lane & 15);
    const int brow = wn * 64 + (lane & 15);
    const int kq = (lane >> 4) * 8;

    for (int k0 = 0; k0 < Kp; k0 += 32) {
        ASYNC_COPY16(Ab + (size_t)r0 * Kp + k0 + q0, As0);
        ASYNC_COPY16(Ab + (size_t)r1 * Kp + k0 + q1, As1);
        ASYNC_COPY16(Bb + (size_t)r0 * Kp + k0 + q0, Bs0);
        ASYNC_COPY16(Bb + (size_t)r1 * Kp + k0 + q1, Bs1);
        __syncthreads();
        short8 af[4], bf[4];
#pragma unroll
        for (int i = 0; i < 4; ++i) af[i] = *(const short8*)&As[(arow + i * 16) * 32 + kq];
#pragma unroll
        for (int j = 0; j < 4; ++j) bf[j] = *(const short8*)&Bs[(brow + j * 16) * 32 + kq];
#pragma unroll
        for (int i = 0; i < 4; ++i)
#pragma unroll
            for (int j = 0; j < 4; ++j)
                acc[i][j] = __builtin_amdgcn_mfma_f32_16x16x32_bf16(af[i], bf[j], acc[i][j], 0, 0, 0);
        __syncthreads();
    }

    const int col = lane & 15;
    const int rq = (lane >> 4) * 4;
#pragma unroll
    for (int i = 0; i < 4; ++i) {
        const int mloc = wm * 64 + i * 16 + rq;
#pragma unroll
        for (int r = 0; r < 4; ++r) {
            const int m = m0 + mloc + r;
            const float bs = bias[m];
#pragma unroll
            for (int j = 0; j < 4; ++j) {
                const int t = t0 + wn * 64 + j * 16 + col;
                out[((size_t)b * 512 + m) * 2048 + t] = acc[i][j][r] + bs;
            }
        }
    }
}

// ---------- fused layer GEMM + residual + channel LayerNorm ----------
// R7 verified optimum: 64-t tile, B staged directly from t-major y planes
// (transpose on the LDS write), XOR swizzle mask(t) = ((t&7)^((t>>3)&7))<<4.
__global__ __launch_bounds__(512, 2) void mgemmln_k(
    const unsigned short* __restrict__ A, const float* __restrict__ bias,
    const unsigned short* __restrict__ Bm, float* __restrict__ z,
    const float* __restrict__ gamr, const float* __restrict__ gami,
    const float* __restrict__ betr, const float* __restrict__ beti, int l)
{
    __shared__ unsigned short Bs[64][512];   // 64KB, swizzled
    __shared__ float biasS[512], gamS[512], betS[512];
    __shared__ float sred[8][64][2];
    __shared__ float sstat[2][64][2];
    const int tid = threadIdx.x;
    const int w = tid >> 6, lane = tid & 63;
    const int t0g = blockIdx.x * 64, b = blockIdx.y;
    unsigned char* BsB = (unsigned char*)&Bs[0][0];

    // ---- stage B from y planes, transpose-on-write ----
    {
        const unsigned short* ysrc = Bm + (size_t)b * 512 * 2048 + t0g;
        const int tseg = lane & 7;       // 8-t segment (t = tseg*8 + j)
        const int rloc = lane >> 3;      // row within the wave's octet
#pragma unroll
        for (int p = 0; p < 8; ++p) {
            const int krow = w * 8 + rloc + p * 64;
            const short8 v = *(const short8*)(ysrc + (size_t)krow * 2048 + tseg * 8);
#pragma unroll
            for (int j = 0; j < 8; ++j) {
                const int t = tseg * 8 + j;
                const int mask = (((t & 7) ^ ((t >> 3) & 7)) << 4);
                *(unsigned short*)(BsB + t * 1024 + ((krow * 2) ^ mask)) =
                    ((const unsigned short*)&v)[j];
            }
        }
        const int m = tid, g = m & 255, comp = m >> 8;
        biasS[m] = bias[m];
        gamS[m] = (comp ? gami : gamr)[l * 256 + g];
        betS[m] = (comp ? beti : betr)[l * 256 + g];
    }
    __syncthreads();

    // ---- K-loop: A direct from global (L2-resident), B from LDS ----
    float4v acc[4][4];
#pragma unroll
    for (int i = 0; i < 4; ++i)
#pragma unroll
        for (int j = 0; j < 4; ++j) acc[i][j] = (float4v){0.f, 0.f, 0.f, 0.f};

    const int brow = lane & 15;
    const int kq8 = (lane >> 4) * 8;
    const unsigned short* Ab = A + ((size_t)(w * 64 + brow)) * 512 + kq8;
    int baseB[4], maskB[4];
#pragma unroll
    for (int j = 0; j < 4; ++j) {
        const int t = j * 16 + brow;
        baseB[j] = t * 1024;
        maskB[j] = (((t & 7) ^ ((t >> 3) & 7)) << 4);
    }

#define LOADF(af_, bf_, k0_) do {                                              \
    _Pragma("unroll")                                                          \
    for (int i = 0; i < 4; ++i)                                                \
        af_[i] = *(const short8*)(Ab + (size_t)i * 16 * 512 + (k0_));          \
    _Pragma("unroll")                                                          \
    for (int j = 0; j < 4; ++j)                                                \
        bf_[j] = *(const short8*)(BsB + baseB[j] + ((((k0_) + kq8) * 2) ^ maskB[j])); \
} while (0)
#define MFMAS(af_, bf_) do {                                                   \
    _Pragma("unroll")                                                          \
    for (int i = 0; i < 4; ++i)                                                \
        _Pragma("unroll")                                                      \
        for (int j = 0; j < 4; ++j)                                            \
            acc[i][j] = __builtin_amdgcn_mfma_f32_16x16x32_bf16(af_[i], bf_[j], acc[i][j], 0, 0, 0); \
} while (0)

    {
        short8 afA[4], bfA[4], afB[4], bfB[4];
        LOADF(afA, bfA, 0);
#pragma unroll 1
        for (int kk = 0; kk < 16; kk += 2) {
            LOADF(afB, bfB, kk * 32 + 32);
            MFMAS(afA, bfA);
            if (kk + 2 < 16) LOADF(afA, bfA, kk * 32 + 64);
            MFMAS(afB, bfB);
        }
    }
#undef LOADF
#undef MFMAS

    // ---- epilogue: v = acc + bias + z_old, LN stats, normalize, write z ----
    const int q4 = (lane >> 4) * 4;
    float4 b4[4], g4[4], e4[4];
#pragma unroll
    for (int i = 0; i < 4; ++i) {
        const int m0 = w * 64 + i * 16 + q4;
        b4[i] = *(const float4*)&biasS[m0];
        g4[i] = *(const float4*)&gamS[m0];
        e4[i] = *(const float4*)&betS[m0];
    }

    float s1[4], s2[4];
#pragma unroll
    for (int j = 0; j < 4; ++j) { s1[j] = 0.f; s2[j] = 0.f; }
#pragma unroll
    for (int j = 0; j < 4; ++j) {
        const int t = t0g + j * 16 + brow;
#pragma unroll
        for (int i = 0; i < 4; ++i) {
            const int m = w * 64 + i * 16 + q4;
            const float* zp = &z[((size_t)b * 512 + m) * 2048 + t];
            const float bb[4] = {b4[i].x, b4[i].y, b4[i].z, b4[i].w};
#pragma unroll
            for (int r = 0; r < 4; ++r) {
                const float v = acc[i][j][r] + bb[r] + zp[(size_t)r * 2048];
                acc[i][j][r] = v;
                s1[j] += v; s2[j] += v * v;
            }
        }
    }
#pragma unroll
    for (int j = 0; j < 4; ++j) {
        s1[j] += __shfl_xor(s1[j], 16); s2[j] += __shfl_xor(s2[j], 16);
        s1[j] += __shfl_xor(s1[j], 32); s2[j] += __shfl_xor(s2[j], 32);
    }
    if (lane < 16) {
#pragma unroll
        for (int j = 0; j < 4; ++j) {
            sred[w][j * 16 + lane][0] = s1[j];
            sred[w][j * 16 + lane][1] = s2[j];
        }
    }
    __syncthreads();
    if (tid < 128) {
        const int t = tid & 63, comp = tid >> 6;
        float S1 = 0.f, S2 = 0.f;
#pragma unroll
        for (int w2 = 0; w2 < 4; ++w2) {
            S1 += sred[comp * 4 + w2][t][0];
            S2 += sred[comp * 4 + w2][t][1];
        }
        const float mn = S1 * (1.f / 256.f);
        const float var = S2 * (1.f / 256.f) - mn * mn;
        sstat[comp][t][0] = mn;
        sstat[comp][t][1] = rsqrtf(var + 1e-5f);
    }
    __syncthreads();
    const int comp = w >> 2;
#pragma unroll
    for (int j = 0; j < 4; ++j) {
        const int tl = j * 16 + brow;
        const float mn = sstat[comp][tl][0], rs = sstat[comp][tl][1];
        const int t = t0g + tl;
#pragma unroll
        for (int i = 0; i < 4; ++i) {
            const int m = w * 64 + i * 16 + q4;
            float* zp = &z[((size_t)b * 512 + m) * 2048 + t];
            const float gg[4] = {g4[i].x, g4[i].y, g4[i].z, g4[i].w};
            const float ee[4] = {e4[i].x, e4[i].y, e4[i].z, e4[i].w};
#pragma unroll
            for (int r = 0; r < 4; ++r)
                zp[(size_t)r * 2048] = (acc[i][j][r] - mn) * rs * gg[r] + ee[r];
        }
    }
}

// ---------- fused decoder: transpose+convert z in-stage, GEMM, paired out ----------
// R13 (verified): ONE block per (t-tile, b); outer loop over 3 m-chunks of
// 384 rows; z staged once. A rows interleaved (m' -> g=m'>>1, comp=m'&1)
// -> float2 {re,im} full-line stores (R7).
__global__ __launch_bounds__(512, 1) void mgemmdec_k(
    const unsigned short* __restrict__ A, const float* __restrict__ bias,
    const float* __restrict__ z, float* __restrict__ out)
{
    __shared__ unsigned short Bs[64][512];   // 64KB, swizzled
    const int tid = threadIdx.x;
    const int w = tid >> 6, lane = tid & 63;
    const int t0g = blockIdx.x * 64, b = blockIdx.y;
    unsigned char* BsB = (unsigned char*)&Bs[0][0];

    // ---- stage B from z fp32 planes: f2bf + transpose-on-write (ONCE) ----
    {
        const float* zsrc = z + (size_t)b * 512 * 2048 + t0g;
        const int tseg = lane & 7, rloc = lane >> 3;
#pragma unroll
        for (int p = 0; p < 8; ++p) {
            const int krow = w * 8 + rloc + p * 64;
            const float* rowp = zsrc + (size_t)krow * 2048 + tseg * 8;
            const float4 va = *(const float4*)rowp;
            const float4 vb = *(const float4*)(rowp + 4);
            const float vals[8] = {va.x, va.y, va.z, va.w, vb.x, vb.y, vb.z, vb.w};
#pragma unroll
            for (int j = 0; j < 8; ++j) {
                const int t = tseg * 8 + j;
                const int mask = (((t & 7) ^ ((t >> 3) & 7)) << 4);
                *(unsigned short*)(BsB + t * 1024 + ((krow * 2) ^ mask)) = f2bf(vals[j]);
            }
        }
    }
    __syncthreads();

    const int brow = lane & 15;
    const int kq8 = (lane >> 4) * 8;
    int baseB[4], maskB[4];
#pragma unroll
    for (int j = 0; j < 4; ++j) {
        const int t = j * 16 + brow;
        baseB[j] = t * 1024;
        maskB[j] = (((t & 7) ^ ((t >> 3) & 7)) << 4);
    }

#define LOADF(af_, bf_, k0_) do {                                              \
    _Pragma("unroll")                                                          \
    for (int i = 0; i < 3; ++i)                                                \
        af_[i] = *(const short8*)(Ab + (size_t)i * 16 * 512 + (k0_));          \
    _Pragma("unroll")                                                          \
    for (int j = 0; j < 4; ++j)                                                \
        bf_[j] = *(const short8*)(BsB + baseB[j] + ((((k0_) + kq8) * 2) ^ maskB[j])); \
} while (0)
#define MFMAS(af_, bf_) do {                                                   \
    _Pragma("unroll")                                                          \
    for (int i = 0; i < 3; ++i)                                                \
        _Pragma("unroll")                                                      \
        for (int j = 0; j < 4; ++j)                                            \
            acc[i][j] = __builtin_amdgcn_mfma_f32_16x16x32_bf16(af_[i], bf_[j], acc[i][j], 0, 0, 0); \
} while (0)

#pragma unroll 1
    for (int mc = 0; mc < 3; ++mc) {
        const int m0b = mc * 384;
        const unsigned short* Ab = A + ((size_t)(m0b + w * 48 + brow)) * 512 + kq8;

        float4v acc[3][4];
#pragma unroll
        for (int i = 0; i < 3; ++i)
#pragma unroll
            for (int j = 0; j < 4; ++j) acc[i][j] = (float4v){0.f, 0.f, 0.f, 0.f};

        {
            short8 afA[3], bfA[4], afB[3], bfB[4];
            LOADF(afA, bfA, 0);
#pragma unroll 1
            for (int kk = 0; kk < 16; kk += 2) {
                LOADF(afB, bfB, kk * 32 + 32);
                MFMAS(afA, bfA);
                if (kk + 2 < 16) LOADF(afA, bfA, kk * 32 + 64);
                MFMAS(afB, bfB);
            }
        }

        // ---- epilogue: bias + paired float2 stores (g<514 guard) ----
        const int q4 = (lane >> 4) * 4;
#pragma unroll
        for (int i = 0; i < 3; ++i) {
            const int mb = m0b + w * 48 + i * 16 + q4;   // even
#pragma unroll
            for (int pr = 0; pr < 2; ++pr) {
                const int m2 = mb + pr * 2;              // even row of the pair
                const int g = m2 >> 1;
                if (g >= 514) continue;
                const float br = bias[m2], bi2 = bias[m2 + 1];
                float* op = out + (((size_t)b * 514 + g) * 2048 + t0g) * 2;
#pragma unroll
                for (int j = 0; j < 4; ++j) {
                    const int tl = j * 16 + brow;
                    const float2 v = make_float2(acc[i][j][pr * 2 + 0] + br,
                                                 acc[i][j][pr * 2 + 1] + bi2);
                    *(float2*)(op + (size_t)tl * 2) = v;
                }
            }
        }
    }
#undef LOADF
#undef MFMAS
}

// ---------- MFMA S4D scan: A=PxU, butterfly states, Y=TriGxU+MxS ----------
// R12 (verified): block per (b,h), U bf16-pair staged, A-agg = PxU via MFMA,
// fp32 butterfly over 64 chunk-aggregates, S split hi+lo bf16,
// Y = TriGxU + MxS_hi + MxS_lo via MFMA.
__global__ __launch_bounds__(256) void s4mm_k(
    const float* __restrict__ z, unsigned short* __restrict__ y,
    const unsigned short* __restrict__ Pmat,
    const float* __restrict__ log_dt, const float* __restrict__ log_A_real,
    const float* __restrict__ A_imag, const float* __restrict__ Dsk, int l)
{
    const int h = blockIdx.x, b = blockIdx.y;
    const int tid = threadIdx.x;
    const int lane = tid & 63, wv = tid >> 6;
    __shared__ float2 wsh[32];
    __shared__ float dsh;
    __shared__ unsigned Ub[64][36];    // u bf16 pairs
    __shared__ unsigned Sb[64][36];    // state hi
    __shared__ unsigned Sc[64][36];    // state lo (residual)
    __shared__ float2 scr[64][33];     // A-agg, then Y

    if (tid < 32) {
        const size_t pidx = ((size_t)l * 256 + h) * 32 + tid;
        const float dt = __expf(log_dt[l * 256 + h]);
        const float Ar = -__expf(log_A_real[pidx]);
        const float Ai = A_imag[pidx];
        const float er = __expf(Ar * dt);
        float sv, cv;
        __sincosf(Ai * dt, &sv, &cv);
        wsh[tid] = make_float2(er * cv, er * sv);
    }
    if (tid == 32) dsh = Dsk[l * 256 + h];

    // ---- stage U: thread owns t = tid*8..+8 = chunk c0q, j0q..+8 ----
    const int c0q = tid >> 2, j0q = (tid & 3) * 8;
    {
        const float* zrp = z + ((size_t)b * 512 + h) * 2048 + tid * 8;
        const float* zip = zrp + 256 * 2048;
        const float4 r0 = *(const float4*)zrp, r1 = *(const float4*)(zrp + 4);
        const float4 i0 = *(const float4*)zip, i1 = *(const float4*)(zip + 4);
        uint4 pa, pb;
        pa.x = cvt_pk_bf16(r0.x, i0.x); pa.y = cvt_pk_bf16(r0.y, i0.y);
        pa.z = cvt_pk_bf16(r0.z, i0.z); pa.w = cvt_pk_bf16(r0.w, i0.w);
        pb.x = cvt_pk_bf16(r1.x, i1.x); pb.y = cvt_pk_bf16(r1.y, i1.y);
        pb.z = cvt_pk_bf16(r1.z, i1.z); pb.w = cvt_pk_bf16(r1.w, i1.w);
        *(uint4*)&Ub[c0q][j0q]     = pa;
        *(uint4*)&Ub[c0q][j0q + 4] = pb;
    }
    __syncthreads();

    const unsigned short* Pg = Pmat + (size_t)h * 12288;
    const int bcol = lane & 15, kq = (lane >> 4) * 8;
    const int arow = (wv * 16 + bcol) * 64 + kq;
    const float2 zero2 = make_float2(0.f, 0.f);

    // ---- matmul1: A-agg = P x U ----
    {
        float4v a1[4];
#pragma unroll
        for (int jf = 0; jf < 4; ++jf) a1[jf] = (float4v){0.f, 0.f, 0.f, 0.f};
#pragma unroll
        for (int k0 = 0; k0 < 64; k0 += 32) {
            const short8 af = *(const short8*)(Pg + arow + k0);
#pragma unroll
            for (int jf = 0; jf < 4; ++jf) {
                const short8 bf = *(const short8*)&Ub[16 * jf + bcol][(k0 + kq) >> 1];
                a1[jf] = __builtin_amdgcn_mfma_f32_16x16x32_bf16(af, bf, a1[jf], 0, 0, 0);
            }
        }
        const int mode0 = (wv * 16 + (lane >> 4) * 4) >> 1;
#pragma unroll
        for (int jf = 0; jf < 4; ++jf) {
            const int c = 16 * jf + bcol;
            scr[c][mode0]     = make_float2(a1[jf][0], a1[jf][1]);
            scr[c][mode0 + 1] = make_float2(a1[jf][2], a1[jf][3]);
        }
    }
    __syncthreads();

    // ---- butterfly scan over 64 chunk-aggregates; wave wv owns 8 modes ----
    {
        const int dstc = (lane + 1) & 63;
#pragma unroll 1
        for (int jm = 0; jm < 8; ++jm) {
            const int n = wv * 8 + jm;
            const float2 wm = wsh[n];
            float2 f = wm;
#pragma unroll
            for (int s = 0; s < 5; ++s) f = cfma(f, f, zero2);   // w^32
            float2 qv = scr[lane][n], pq = f;
#pragma unroll
            for (int s = 0; s < 6; ++s) {
                const int d = 1 << s;
                float2 sh;
                sh.x = __shfl_up(qv.x, (unsigned)d);
                sh.y = __shfl_up(qv.y, (unsigned)d);
                const float2 qn = cfma(pq, sh, qv);
                if (lane >= d) qv = qn;
                pq = cfma(pq, pq, zero2);
            }
            // exclusive via store-to-lane+1; split hi/lo bf16
            const unsigned hi = cvt_pk_bf16(qv.x, qv.y);
            const float2 hv = unpk(hi);
            const unsigned lo = cvt_pk_bf16(qv.x - hv.x, qv.y - hv.y);
            Sb[dstc][n] = (lane == 63) ? 0u : hi;
            Sc[dstc][n] = (lane == 63) ? 0u : lo;
        }
    }
    __syncthreads();

    // ---- matmul2+3: Y = TriG x U + M x S_hi + M x S_lo ----
    {
        const unsigned short* Tg = Pg + 4096;
        const unsigned short* Mg = Pg + 8192;
        float4v a2[4];
#pragma unroll
        for (int jf = 0; jf < 4; ++jf) a2[jf] = (float4v){0.f, 0.f, 0.f, 0.f};
#pragma unroll
        for (int k0 = 0; k0 < 64; k0 += 32) {
            const short8 af = *(const short8*)(Tg + arow + k0);
#pragma unroll
            for (int jf = 0; jf < 4; ++jf) {
                const short8 bf = *(const short8*)&Ub[16 * jf + bcol][(k0 + kq) >> 1];
                a2[jf] = __builtin_amdgcn_mfma_f32_16x16x32_bf16(af, bf, a2[jf], 0, 0, 0);
            }
        }
#pragma unroll
        for (int k0 = 0; k0 < 64; k0 += 32) {
            const short8 af = *(const short8*)(Mg + arow + k0);
#pragma unroll
            for (int jf = 0; jf < 4; ++jf) {
                const short8 bf = *(const short8*)&Sb[16 * jf + bcol][(k0 + kq) >> 1];
                a2[jf] = __builtin_amdgcn_mfma_f32_16x16x32_bf16(af, bf, a2[jf], 0, 0, 0);
            }
        }
#pragma unroll
        for (int k0 = 0; k0 < 64; k0 += 32) {
            const short8 af = *(const short8*)(Mg + arow + k0);
#pragma unroll
            for (int jf = 0; jf < 4; ++jf) {
                const short8 bf = *(const short8*)&Sc[16 * jf + bcol][(k0 + kq) >> 1];
                a2[jf] = __builtin_amdgcn_mfma_f32_16x16x32_bf16(af, bf, a2[jf], 0, 0, 0);
            }
        }
        __syncthreads();   // scr (A-agg) fully consumed; reuse as Y
        const int jp0 = (wv * 16 + (lane >> 4) * 4) >> 1;
#pragma unroll
        for (int jf = 0; jf < 4; ++jf) {
            const int c = 16 * jf + bcol;
            scr[c][jp0]     = make_float2(a2[jf][0], a2[jf][1]);
            scr[c][jp0 + 1] = make_float2(a2[jf][2], a2[jf][3]);
        }
    }
    __syncthreads();

    // ---- final: D-skip + gelu + bf16 pack + coalesced stores ----
    {
        const float dv = dsh;
        unsigned short* yrp = y + ((size_t)b * 512 + h) * 2048 + tid * 8;
        unsigned short* yip = yrp + 256 * 2048;
        short8 vr8, vi8;
#pragma unroll
        for (int j = 0; j < 8; ++j) {
            const float2 yv = scr[c0q][j0q + j];
            const float2 uv = unpk(Ub[c0q][j0q + j]);
            ((unsigned short*)&vr8)[j] = f2bf(gelu_tanh(__builtin_fmaf(dv, uv.x, yv.x)));
            ((unsigned short*)&vi8)[j] = f2bf(gelu_tanh(__builtin_fmaf(dv, uv.y, yv.y)));
        }
        *(short8*)yrp = vr8;
        *(short8*)yip = vi8;
    }
}

extern "C" void kernel_launch(void* const* d_in, const int* in_sizes, int n_in,
                              void* d_out, int out_size, void* d_ws, size_t ws_size,
                              hipStream_t stream)
{
    const float* x        = (const float*)d_in[0];
    const float* enc_Wr   = (const float*)d_in[1];
    const float* enc_Wi   = (const float*)d_in[2];
    const float* enc_br   = (const float*)d_in[3];
    const float* enc_bi   = (const float*)d_in[4];
    const float* log_dt   = (const float*)d_in[5];
    const float* log_A_r  = (const float*)d_in[6];
    const float* A_imag   = (const float*)d_in[7];
    const float* C_r      = (const float*)d_in[8];
    const float* C_i      = (const float*)d_in[9];
    const float* Dp       = (const float*)d_in[10];
    const float* out_Wr   = (const float*)d_in[11];
    const float* out_Wi   = (const float*)d_in[12];
    const float* out_br   = (const float*)d_in[13];
    const float* out_bi   = (const float*)d_in[14];
    const float* ln_gr    = (const float*)d_in[15];
    const float* ln_gi    = (const float*)d_in[16];
    const float* ln_br    = (const float*)d_in[17];
    const float* ln_bi    = (const float*)d_in[18];
    const float* dec_Wr   = (const float*)d_in[19];
    const float* dec_Wi   = (const float*)d_in[20];
    const float* dec_br   = (const float*)d_in[21];
    const float* dec_bi   = (const float*)d_in[22];

    // ---- workspace layout (bytes) ----
    uint8_t* W = (uint8_t*)d_ws;
    float* z             = (float*)W;                       // 33,554,432
    unsigned short* Pmat = (unsigned short*)(W + 33554432); // 256x3x4096x2 = 6,291,456 (rebuilt per layer)
    unsigned short* A_enc= (unsigned short*)(W + 50331648); // 512x1056x2  = 1,081,344
    unsigned short* A_lay= (unsigned short*)(W + 51412992); // 4x512x512x2 = 2,097,152
    unsigned short* A_dec= (unsigned short*)(W + 53510144); // 1152x512x2  = 1,179,648
    float* b_enc         = (float*)(W + 54689792);          // 512 f
    float* b_lay         = (float*)(W + 54691840);          // 2048 f
    float* b_dec         = (float*)(W + 54700032);          // 1028 f

    // ---- d_out doubles as scratch ----
    unsigned short* y   = (unsigned short*)((uint8_t*)d_out + 33554432);   // 16,777,216
    unsigned short* xp  = (unsigned short*)d_out;  // 34,603,008; dead after encoder GEMM

    // ---- build all weights/biases in one launch ----
    buildall_k<<<8527, 256, 0, stream>>>(enc_Wr, enc_Wi, out_Wr, out_Wi,
                                         dec_Wr, dec_Wi, enc_br, enc_bi,
                                         out_br, out_bi, dec_br, dec_bi,
                                         A_enc, A_lay, A_dec,
                                         b_enc, b_lay, b_dec);

    // ---- encoder: pack x -> xp, GEMM -> z ----
    packx_k<<<dim3(32, 9, 8), 256, 0, stream>>>(x, xp);
    mgemm_k<<<dim3(4, 16, 8), 256, 0, stream>>>(A_enc, b_enc, xp, z, 512, 1056);

    // ---- layers: scan-matrices -> MFMA scan -> fused GEMM+residual+LN ----
    for (int l = 0; l < 4; ++l) {
        buildmm_k<<<256, 256, 0, stream>>>(log_dt, log_A_r, A_imag, C_r, C_i, Pmat, l);
        s4mm_k<<<dim3(256, 8), 256, 0, stream>>>(z, y, Pmat, log_dt, log_A_r,
                                                 A_imag, Dp, l);
        mgemmln_k<<<dim3(32, 8), 512, 0, stream>>>(A_lay + (size_t)l * 262144,
                                                   b_lay + l * 512, y, z,
                                                   ln_gr, ln_gi, ln_br, ln_bi, l);
    }

    // ---- decoder: single-pass fused transpose+convert+GEMM -> d_out ----
    mgemmdec_k<<<dim3(32, 8), 512, 0, stream>>>(A_dec, b_dec, z, (float*)d_out);
}

// Round 16
// 523.000 us; speedup vs baseline: 1.0156x; 1.0020x over previous
//
#include <hip/hip_runtime.h>
#include <cstddef>
#include <cstdint>

// B=8, C=2, Hf=257, T=2048, D_IN=514, DM=256, NL=4, N=32
// Activations: fp32 planes (b, 2*DM=512, T). GEMMs run bf16 MFMA.
// R16: s4mm restructure -- TriG x U (independent of the butterfly) hoisted
// into phase 1, sharing Ub fragment loads with P x U (1 bf read -> 2 MFMAs);
// Y accumulator carried in registers across the butterfly; one barrier
// dropped (5 -> 4). Same arithmetic, pure reordering.

typedef __attribute__((ext_vector_type(8))) short short8;
typedef __attribute__((ext_vector_type(4))) float float4v;

__device__ __forceinline__ unsigned short f2bf(float f) {
    union { float f; unsigned u; } v; v.f = f;
    const unsigned r = v.u + 0x7fffu + ((v.u >> 16) & 1u);  // RNE
    return (unsigned short)(r >> 16);
}

__device__ __forceinline__ float gelu_tanh(float x) {
    const float x3 = x * x * x;
    const float v  = 0.7978845608028654f * (x + 0.044715f * x3);
    const float e  = __expf(2.f * v);
    const float th = 1.f - 2.f / (e + 1.f);
    return 0.5f * x * (1.f + th);
}

// packed bf16 pair: dst.lo = bf16(lo), dst.hi = bf16(hi) (RNE)
__device__ __forceinline__ unsigned cvt_pk_bf16(float lo, float hi) {
    unsigned r;
    asm("v_cvt_pk_bf16_f32 %0, %1, %2" : "=v"(r) : "v"(lo), "v"(hi));
    return r;
}
// unpack bf16x2 dword -> float2 (exact)
__device__ __forceinline__ float2 unpk(unsigned d) {
    float2 u;
    u.x = __uint_as_float(d << 16);
    u.y = __uint_as_float(d & 0xffff0000u);
    return u;
}

// packed complex mul-add: w (*) p + u via 2x v_pk_fma_f32
__device__ __forceinline__ float2 cfma(const float2 w, const float2 p,
                                       const float2 u) {
    float2 t, r;
    asm("v_pk_fma_f32 %0, %1, %2, %3 op_sel:[1,1,0] op_sel_hi:[1,0,1] neg_lo:[1,0,0] neg_hi:[0,0,0]"
        : "=v"(t) : "v"(w), "v"(p), "v"(u));
    asm("v_pk_fma_f32 %0, %1, %2, %3 op_sel:[0,0,0] op_sel_hi:[0,1,1]"
        : "=v"(r) : "v"(w), "v"(p), "v"(t));
    return r;
}

#define ASYNC_COPY16(gp, lp) __builtin_amdgcn_global_load_lds( \
    (const __attribute__((address_space(1))) unsigned int*)(gp), \
    (__attribute__((address_space(3))) unsigned int*)(lp), 16, 0, 0)

// ---------- ONE builder launch for all weights/biases ----------
__global__ __launch_bounds__(256) void buildall_k(
    const float* __restrict__ enc_Wr, const float* __restrict__ enc_Wi,
    const float* __restrict__ out_Wr, const float* __restrict__ out_Wi,
    const float* __restrict__ dec_Wr, const float* __restrict__ dec_Wi,
    const float* __restrict__ enc_br, const float* __restrict__ enc_bi,
    const float* __restrict__ out_br, const float* __restrict__ out_bi,
    const float* __restrict__ dec_br, const float* __restrict__ dec_bi,
    unsigned short* __restrict__ A_enc, unsigned short* __restrict__ A_lay,
    unsigned short* __restrict__ A_dec,
    float* __restrict__ b_enc, float* __restrict__ b_lay,
    float* __restrict__ b_dec)
{
    int blk = blockIdx.x;
    const int tid = threadIdx.x;
    if (blk < 2112) {
        const int i = blk * 256 + tid;
        const int m = i / 1056, k = i - m * 1056;
        const int ri = m >= 256, g = m & 255;
        const int blk2 = k >= 528;
        const int hh = k - blk2 * 528;
        float val = 0.f;
        if (hh < 514) {
            const float wr = enc_Wr[(size_t)g * 514 + hh];
            const float wi = enc_Wi[(size_t)g * 514 + hh];
            val = ri ? (blk2 ? wr : wi) : (blk2 ? -wi : wr);
        }
        A_enc[i] = f2bf(val);
        return;
    }
    blk -= 2112;
    if (blk < 4096) {
        const int l = blk >> 10;
        const int i = ((blk & 1023) << 8) + tid;
        const float* Wr = out_Wr + (size_t)l * 65536;
        const float* Wi = out_Wi + (size_t)l * 65536;
        const int m = i >> 9, k = i & 511;
        const int ri = m >= 256, g = m & 255;
        const int blk2 = k >> 8, hh = k & 255;
        const float wr = Wr[(size_t)g * 256 + hh];
        const float wi = Wi[(size_t)g * 256 + hh];
        A_lay[(size_t)l * 262144 + i] =
            f2bf(ri ? (blk2 ? wr : wi) : (blk2 ? -wi : wr));
        return;
    }
    blk -= 4096;
    if (blk < 2304) {
        // decoder W, INTERLEAVED rows: m' -> (g = m'>>1, comp = m'&1).
        const int i = blk * 256 + tid;
        const int m = i >> 9, k = i & 511;
        const int g = m >> 1, comp = m & 1;
        float val = 0.f;
        if (g < 514) {
            const int blk2 = k >> 8, hh = k & 255;
            const float wr = dec_Wr[(size_t)g * 256 + hh];
            const float wi = dec_Wi[(size_t)g * 256 + hh];
            val = comp ? (blk2 ? wr : wi) : (blk2 ? -wi : wr);
        }
        A_dec[i] = f2bf(val);
        return;
    }
    blk -= 2304;
    if (blk < 2) {
        const int i = blk * 256 + tid;
        b_enc[i] = (i < 256) ? enc_br[i] : enc_bi[i - 256];
        return;
    }
    blk -= 2;
    if (blk < 8) {
        const int l = blk >> 1;
        const int i = ((blk & 1) << 8) + tid;
        b_lay[l * 512 + i] = (i < 256) ? out_br[l * 256 + i]
                                       : out_bi[l * 256 + i - 256];
        return;
    }
    blk -= 8;
    {
        const int i = blk * 256 + tid;
        if (i < 1028) b_dec[i] = (i & 1) ? dec_bi[i >> 1] : dec_br[i >> 1];
    }
}

// ---------- per-layer scan-matrix builder: P / TriG / M per h ----------
// Pmat layout: [h][3][64*64] bf16, rows/cols interleaved re/im:
// entry(2a+ri, 2b+ci) of complex coef v: ri=0:(Re,-Im) ri=1:(Im,Re).
__global__ __launch_bounds__(256) void buildmm_k(
    const float* __restrict__ log_dt, const float* __restrict__ log_A_real,
    const float* __restrict__ A_imag, const float* __restrict__ C_r,
    const float* __restrict__ C_i, unsigned short* __restrict__ Pmat, int l)
{
    const int h = blockIdx.x;
    const int tid = threadIdx.x;
    __shared__ float2 pw[32][33];
    __shared__ float2 csh[32], gsh[32];

    if (tid < 32) {
        const size_t pidx = ((size_t)l * 256 + h) * 32 + tid;
        const float dt = __expf(log_dt[l * 256 + h]);
        const float Ar = -__expf(log_A_real[pidx]);
        const float Ai = A_imag[pidx];
        const float er = __expf(Ar * dt);
        float sv, cv;
        __sincosf(Ai * dt, &sv, &cv);
        const float wr = er * cv, wi = er * sv;
        const float den = 1.f / (Ar * Ar + Ai * Ai);
        const float nr = wr - 1.f, ni = wi;
        const float qr = (nr * Ar + ni * Ai) * den;
        const float qi = (ni * Ar - nr * Ai) * den;
        const float cr = C_r[pidx], ci = C_i[pidx];
        csh[tid] = make_float2(cr * qr - ci * qi, cr * qi + ci * qr);
        float2 p = make_float2(1.f, 0.f);
        const float2 w = make_float2(wr, wi);
#pragma unroll 1
        for (int k = 0; k < 33; ++k) {
            pw[tid][k] = p;
            const float pr = p.x * w.x - p.y * w.y;
            p.y = p.x * w.y + p.y * w.x;
            p.x = pr;
        }
    }
    __syncthreads();
    if (tid < 32) {
        float2 g = make_float2(0.f, 0.f);
#pragma unroll 1
        for (int n = 0; n < 32; ++n) {
            const float2 c = csh[n], p = pw[n][tid];
            g.x += c.x * p.x - c.y * p.y;
            g.y += c.x * p.y + c.y * p.x;
        }
        gsh[tid] = g;
    }
    __syncthreads();

    unsigned short* base = Pmat + (size_t)h * 12288;
    const int row = tid >> 2, cq = (tid & 3) * 16;
    const int half = row & 1, src = row >> 1;
#pragma unroll 1
    for (int c = cq; c < cq + 16; ++c) {
        const int ci = c & 1, idx = c >> 1;
        const float2 v = pw[src][31 - idx];
        base[row * 64 + c] = f2bf(half ? (ci ? v.x : v.y) : (ci ? -v.y : v.x));
        const float2 g = (idx <= src) ? gsh[src - idx] : make_float2(0.f, 0.f);
        base[4096 + row * 64 + c] = f2bf(half ? (ci ? g.x : g.y) : (ci ? -g.y : g.x));
        const float2 wp = pw[idx][src + 1];
        const float2 cc = csh[idx];
        const float2 e = make_float2(cc.x * wp.x - cc.y * wp.y,
                                     cc.x * wp.y + cc.y * wp.x);
        base[8192 + row * 64 + c] = f2bf(half ? (ci ? e.x : e.y) : (ci ? -e.y : e.x));
    }
}

// ---------- encoder input pack: x (b,514,T,2) fp32 -> xp (b,T,1056) bf16 ----------
__global__ __launch_bounds__(256) void packx_k(const float* __restrict__ x,
                                               unsigned short* __restrict__ xp)
{
    const int t0 = blockIdx.x * 64, d0 = blockIdx.y * 64, b = blockIdx.z;
    __shared__ unsigned short tr_[64][72];
    __shared__ unsigned short ti_[64][72];
    const int tid = threadIdx.x;
    const int tp = tid & 31, dl0 = tid >> 5;
#pragma unroll
    for (int p = 0; p < 8; ++p) {
        const int d = dl0 + p * 8;
        const int gd = d0 + d;
        float4 v = make_float4(0.f, 0.f, 0.f, 0.f);
        if (gd < 514) v = *(const float4*)(x + (((size_t)b * 514 + gd) * 2048 + t0 + tp * 2) * 2);
        tr_[tp * 2 + 0][d] = f2bf(v.x); ti_[tp * 2 + 0][d] = f2bf(v.y);
        tr_[tp * 2 + 1][d] = f2bf(v.z); ti_[tp * 2 + 1][d] = f2bf(v.w);
    }
    __syncthreads();
    const int dc = tid & 7;
    const int kloc = d0 + dc * 8;
    if (kloc < 528) {
#pragma unroll
        for (int p = 0; p < 2; ++p) {
            const int t = (tid >> 3) + p * 32;
            const size_t rowb = ((size_t)b * 2048 + t0 + t) * 1056;
            *(short8*)&xp[rowb + kloc]       = *(const short8*)&tr_[t][dc * 8];
            *(short8*)&xp[rowb + 528 + kloc] = *(const short8*)&ti_[t][dc * 8];
        }
    }
}

// ---------- bf16 MFMA GEMM (encoder): out(b,M,T) = A * Bm^T + bias ----------
__global__ __launch_bounds__(256, 2) void mgemm_k(
    const unsigned short* __restrict__ A, const float* __restrict__ bias,
    const unsigned short* __restrict__ Bm, float* __restrict__ out,
    int M, int Kp)
{
    __shared__ unsigned short As[4096];  // [m 0..127][k 0..31]
    __shared__ unsigned short Bs[4096];  // [t 0..127][k 0..31]
    const int tid = threadIdx.x;
    const int w = tid >> 6, lane = tid & 63;
    const int m0 = blockIdx.x * 128, t0 = blockIdx.y * 128, b = blockIdx.z;
    const int wm = w & 1, wn = w >> 1;

    const unsigned short* Ab = A + (size_t)m0 * Kp;
    const unsigned short* Bb = Bm + ((size_t)b * 2048 + t0) * Kp;

    const int c0 = w * 64 + lane;
    const int r0 = c0 >> 2, q0 = (c0 & 3) * 8;
    const int c1 = c0 + 256;
    const int r1 = c1 >> 2, q1 = (c1 & 3) * 8;
    unsigned short* As0 = &As[(size_t)(w * 64) * 8];
    unsigned short* As1 = &As[(size_t)(w * 64 + 256) * 8];
    unsigned short* Bs0 = &Bs[(size_t)(w * 64) * 8];
    unsigned short* Bs1 = &Bs[(size_t)(w * 64 + 256) * 8];

    float4v acc[4][4];
#pragma unroll
    for (int i = 0; i < 4; ++i)
#pragma unroll
        for (int j = 0; j < 4; ++j) acc[i][j] = (float4v){0.f, 0.f, 0.f, 0.f};

    const int arow = wm * 64 + (lane & 15);
    const int brow = wn * 64 + (lane & 15);
    const int kq = (lane >> 4) * 8;

    for (int k0 = 0; k0 < Kp; k0 += 32) {
        ASYNC_COPY16(Ab + (size_t)r0 * Kp + k0 + q0, As0);
        ASYNC_COPY16(Ab + (size_t)r1 * Kp + k0 + q1, As1);
        ASYNC_COPY16(Bb + (size_t)r0 * Kp + k0 + q0, Bs0);
        ASYNC_COPY16(Bb + (size_t)r1 * Kp + k0 + q1, Bs1);
        __syncthreads();
        short8 af[4], bf[4];
#pragma unroll
        for (int i = 0; i < 4; ++i) af[i] = *(const short8*)&As[(arow + i * 16) * 32 + kq];
#pragma unroll
        for (int j = 0; j < 4; ++j) bf[j] = *(const short8*)&Bs[(brow + j * 16) * 32 + kq];
#pragma unroll
        for (int i = 0; i < 4; ++i)
#pragma unroll
            for (int j = 0; j < 4; ++j)
                acc[i][j] = __builtin_amdgcn_mfma_f32_16x16x32_bf16(af[i], bf[j], acc[i][j], 0, 0, 0);
        __syncthreads();
    }

    const int col = lane & 15;
    const int rq = (lane >> 4) * 4;
#pragma unroll
    for (int i = 0; i < 4; ++i) {
        const int mloc = wm * 64 + i * 16 + rq;
#pragma unroll
        for (int r = 0; r < 4; ++r) {
            const int m = m0 + mloc + r;
            const float bs = bias[m];
#pragma unroll
            for (int j = 0; j < 4; ++j) {
                const int t = t0 + wn * 64 + j * 16 + col;
                out[((size_t)b * 512 + m) * 2048 + t] = acc[i][j][r] + bs;
            }
        }
    }
}

// ---------- fused layer GEMM + residual + channel LayerNorm ----------
// R7 verified optimum: 64-t tile, B staged directly from t-major y planes
// (transpose on the LDS write), XOR swizzle mask(t) = ((t&7)^((t>>3)&7))<<4.
__global__ __launch_bounds__(512, 2) void mgemmln_k(
    const unsigned short* __restrict__ A, const float* __restrict__ bias,
    const unsigned short* __restrict__ Bm, float* __restrict__ z,
    const float* __restrict__ gamr, const float* __restrict__ gami,
    const float* __restrict__ betr, const float* __restrict__ beti, int l)
{
    __shared__ unsigned short Bs[64][512];   // 64KB, swizzled
    __shared__ float biasS[512], gamS[512], betS[512];
    __shared__ float sred[8][64][2];
    __shared__ float sstat[2][64][2];
    const int tid = threadIdx.x;
    const int w = tid >> 6, lane = tid & 63;
    const int t0g = blockIdx.x * 64, b = blockIdx.y;
    unsigned char* BsB = (unsigned char*)&Bs[0][0];

    // ---- stage B from y planes, transpose-on-write ----
    {
        const unsigned short* ysrc = Bm + (size_t)b * 512 * 2048 + t0g;
        const int tseg = lane & 7;       // 8-t segment (t = tseg*8 + j)
        const int rloc = lane >> 3;      // row within the wave's octet
#pragma unroll
        for (int p = 0; p < 8; ++p) {
            const int krow = w * 8 + rloc + p * 64;
            const short8 v = *(const short8*)(ysrc + (size_t)krow * 2048 + tseg * 8);
#pragma unroll
            for (int j = 0; j < 8; ++j) {
                const int t = tseg * 8 + j;
                const int mask = (((t & 7) ^ ((t >> 3) & 7)) << 4);
                *(unsigned short*)(BsB + t * 1024 + ((krow * 2) ^ mask)) =
                    ((const unsigned short*)&v)[j];
            }
        }
        const int m = tid, g = m & 255, comp = m >> 8;
        biasS[m] = bias[m];
        gamS[m] = (comp ? gami : gamr)[l * 256 + g];
        betS[m] = (comp ? beti : betr)[l * 256 + g];
    }
    __syncthreads();

    // ---- K-loop: A direct from global (L2-resident), B from LDS ----
    float4v acc[4][4];
#pragma unroll
    for (int i = 0; i < 4; ++i)
#pragma unroll
        for (int j = 0; j < 4; ++j) acc[i][j] = (float4v){0.f, 0.f, 0.f, 0.f};

    const int brow = lane & 15;
    const int kq8 = (lane >> 4) * 8;
    const unsigned short* Ab = A + ((size_t)(w * 64 + brow)) * 512 + kq8;
    int baseB[4], maskB[4];
#pragma unroll
    for (int j = 0; j < 4; ++j) {
        const int t = j * 16 + brow;
        baseB[j] = t * 1024;
        maskB[j] = (((t & 7) ^ ((t >> 3) & 7)) << 4);
    }

#define LOADF(af_, bf_, k0_) do {                                              \
    _Pragma("unroll")                                                          \
    for (int i = 0; i < 4; ++i)                                                \
        af_[i] = *(const short8*)(Ab + (size_t)i * 16 * 512 + (k0_));          \
    _Pragma("unroll")                                                          \
    for (int j = 0; j < 4; ++j)                                                \
        bf_[j] = *(const short8*)(BsB + baseB[j] + ((((k0_) + kq8) * 2) ^ maskB[j])); \
} while (0)
#define MFMAS(af_, bf_) do {                                                   \
    _Pragma("unroll")                                                          \
    for (int i = 0; i < 4; ++i)                                                \
        _Pragma("unroll")                                                      \
        for (int j = 0; j < 4; ++j)                                            \
            acc[i][j] = __builtin_amdgcn_mfma_f32_16x16x32_bf16(af_[i], bf_[j], acc[i][j], 0, 0, 0); \
} while (0)

    {
        short8 afA[4], bfA[4], afB[4], bfB[4];
        LOADF(afA, bfA, 0);
#pragma unroll 1
        for (int kk = 0; kk < 16; kk += 2) {
            LOADF(afB, bfB, kk * 32 + 32);
            MFMAS(afA, bfA);
            if (kk + 2 < 16) LOADF(afA, bfA, kk * 32 + 64);
            MFMAS(afB, bfB);
        }
    }
#undef LOADF
#undef MFMAS

    // ---- epilogue: v = acc + bias + z_old, LN stats, normalize, write z ----
    const int q4 = (lane >> 4) * 4;
    float4 b4[4], g4[4], e4[4];
#pragma unroll
    for (int i = 0; i < 4; ++i) {
        const int m0 = w * 64 + i * 16 + q4;
        b4[i] = *(const float4*)&biasS[m0];
        g4[i] = *(const float4*)&gamS[m0];
        e4[i] = *(const float4*)&betS[m0];
    }

    float s1[4], s2[4];
#pragma unroll
    for (int j = 0; j < 4; ++j) { s1[j] = 0.f; s2[j] = 0.f; }
#pragma unroll
    for (int j = 0; j < 4; ++j) {
        const int t = t0g + j * 16 + brow;
#pragma unroll
        for (int i = 0; i < 4; ++i) {
            const int m = w * 64 + i * 16 + q4;
            const float* zp = &z[((size_t)b * 512 + m) * 2048 + t];
            const float bb[4] = {b4[i].x, b4[i].y, b4[i].z, b4[i].w};
#pragma unroll
            for (int r = 0; r < 4; ++r) {
                const float v = acc[i][j][r] + bb[r] + zp[(size_t)r * 2048];
                acc[i][j][r] = v;
                s1[j] += v; s2[j] += v * v;
            }
        }
    }
#pragma unroll
    for (int j = 0; j < 4; ++j) {
        s1[j] += __shfl_xor(s1[j], 16); s2[j] += __shfl_xor(s2[j], 16);
        s1[j] += __shfl_xor(s1[j], 32); s2[j] += __shfl_xor(s2[j], 32);
    }
    if (lane < 16) {
#pragma unroll
        for (int j = 0; j < 4; ++j) {
            sred[w][j * 16 + lane][0] = s1[j];
            sred[w][j * 16 + lane][1] = s2[j];
        }
    }
    __syncthreads();
    if (tid < 128) {
        const int t = tid & 63, comp = tid >> 6;
        float S1 = 0.f, S2 = 0.f;
#pragma unroll
        for (int w2 = 0; w2 < 4; ++w2) {
            S1 += sred[comp * 4 + w2][t][0];
            S2 += sred[comp * 4 + w2][t][1];
        }
        const float mn = S1 * (1.f / 256.f);
        const float var = S2 * (1.f / 256.f) - mn * mn;
        sstat[comp][t][0] = mn;
        sstat[comp][t][1] = rsqrtf(var + 1e-5f);
    }
    __syncthreads();
    const int comp = w >> 2;
#pragma unroll
    for (int j = 0; j < 4; ++j) {
        const int tl = j * 16 + brow;
        const float mn = sstat[comp][tl][0], rs = sstat[comp][tl][1];
        const int t = t0g + tl;
#pragma unroll
        for (int i = 0; i < 4; ++i) {
            const int m = w * 64 + i * 16 + q4;
            float* zp = &z[((size_t)b * 512 + m) * 2048 + t];
            const float gg[4] = {g4[i].x, g4[i].y, g4[i].z, g4[i].w};
            const float ee[4] = {e4[i].x, e4[i].y, e4[i].z, e4[i].w};
#pragma unroll
            for (int r = 0; r < 4; ++r)
                zp[(size_t)r * 2048] = (acc[i][j][r] - mn) * rs * gg[r] + ee[r];
        }
    }
}

// ---------- fused decoder: transpose+convert z in-stage, GEMM, paired out ----------
// R13 (verified): ONE block per (t-tile, b); outer loop over 3 m-chunks of
// 384 rows; z staged once. A rows interleaved (m' -> g=m'>>1, comp=m'&1)
// -> float2 {re,im} full-line stores (R7).
__global__ __launch_bounds__(512, 1) void mgemmdec_k(
    const unsigned short* __restrict__ A, const float* __restrict__ bias,
    const float* __restrict__ z, float* __restrict__ out)
{
    __shared__ unsigned short Bs[64][512];   // 64KB, swizzled
    const int tid = threadIdx.x;
    const int w = tid >> 6, lane = tid & 63;
    const int t0g = blockIdx.x * 64, b = blockIdx.y;
    unsigned char* BsB = (unsigned char*)&Bs[0][0];

    // ---- stage B from z fp32 planes: f2bf + transpose-on-write (ONCE) ----
    {
        const float* zsrc = z + (size_t)b * 512 * 2048 + t0g;
        const int tseg = lane & 7, rloc = lane >> 3;
#pragma unroll
        for (int p = 0; p < 8; ++p) {
            const int krow = w * 8 + rloc + p * 64;
            const float* rowp = zsrc + (size_t)krow * 2048 + tseg * 8;
            const float4 va = *(const float4*)rowp;
            const float4 vb = *(const float4*)(rowp + 4);
            const float vals[8] = {va.x, va.y, va.z, va.w, vb.x, vb.y, vb.z, vb.w};
#pragma unroll
            for (int j = 0; j < 8; ++j) {
                const int t = tseg * 8 + j;
                const int mask = (((t & 7) ^ ((t >> 3) & 7)) << 4);
                *(unsigned short*)(BsB + t * 1024 + ((krow * 2) ^ mask)) = f2bf(vals[j]);
            }
        }
    }
    __syncthreads();

    const int brow = lane & 15;
    const int kq8 = (lane >> 4) * 8;
    int baseB[4], maskB[4];
#pragma unroll
    for (int j = 0; j < 4; ++j) {
        const int t = j * 16 + brow;
        baseB[j] = t * 1024;
        maskB[j] = (((t & 7) ^ ((t >> 3) & 7)) << 4);
    }

#define LOADF(af_, bf_, k0_) do {                                              \
    _Pragma("unroll")                                                          \
    for (int i = 0; i < 3; ++i)                                                \
        af_[i] = *(const short8*)(Ab + (size_t)i * 16 * 512 + (k0_));          \
    _Pragma("unroll")                                                          \
    for (int j = 0; j < 4; ++j)                                                \
        bf_[j] = *(const short8*)(BsB + baseB[j] + ((((k0_) + kq8) * 2) ^ maskB[j])); \
} while (0)
#define MFMAS(af_, bf_) do {                                                   \
    _Pragma("unroll")                                                          \
    for (int i = 0; i < 3; ++i)                                                \
        _Pragma("unroll")                                                      \
        for (int j = 0; j < 4; ++j)                                            \
            acc[i][j] = __builtin_amdgcn_mfma_f32_16x16x32_bf16(af_[i], bf_[j], acc[i][j], 0, 0, 0); \
} while (0)

#pragma unroll 1
    for (int mc = 0; mc < 3; ++mc) {
        const int m0b = mc * 384;
        const unsigned short* Ab = A + ((size_t)(m0b + w * 48 + brow)) * 512 + kq8;

        float4v acc[3][4];
#pragma unroll
        for (int i = 0; i < 3; ++i)
#pragma unroll
            for (int j = 0; j < 4; ++j) acc[i][j] = (float4v){0.f, 0.f, 0.f, 0.f};

        {
            short8 afA[3], bfA[4], afB[3], bfB[4];
            LOADF(afA, bfA, 0);
#pragma unroll 1
            for (int kk = 0; kk < 16; kk += 2) {
                LOADF(afB, bfB, kk * 32 + 32);
                MFMAS(afA, bfA);
                if (kk + 2 < 16) LOADF(afA, bfA, kk * 32 + 64);
                MFMAS(afB, bfB);
            }
        }

        // ---- epilogue: bias + paired float2 stores (g<514 guard) ----
        const int q4 = (lane >> 4) * 4;
#pragma unroll
        for (int i = 0; i < 3; ++i) {
            const int mb = m0b + w * 48 + i * 16 + q4;   // even
#pragma unroll
            for (int pr = 0; pr < 2; ++pr) {
                const int m2 = mb + pr * 2;              // even row of the pair
                const int g = m2 >> 1;
                if (g >= 514) continue;
                const float br = bias[m2], bi2 = bias[m2 + 1];
                float* op = out + (((size_t)b * 514 + g) * 2048 + t0g) * 2;
#pragma unroll
                for (int j = 0; j < 4; ++j) {
                    const int tl = j * 16 + brow;
                    const float2 v = make_float2(acc[i][j][pr * 2 + 0] + br,
                                                 acc[i][j][pr * 2 + 1] + bi2);
                    *(float2*)(op + (size_t)tl * 2) = v;
                }
            }
        }
    }
#undef LOADF
#undef MFMAS
}

// ---------- MFMA S4D scan: {A-agg,Ytri}=\{P,TriG\}xU, butterfly, Y+=MxS ----------
// R16: TriG x U hoisted into phase 1 (shares Ub fragment loads with P x U;
// 1 bf read -> 2 MFMAs), Y accumulator a2 carried in registers across the
// butterfly; post-butterfly phase is only M x S_hi + M x S_lo. 4 barriers.
__global__ __launch_bounds__(256) void s4mm_k(
    const float* __restrict__ z, unsigned short* __restrict__ y,
    const unsigned short* __restrict__ Pmat,
    const float* __restrict__ log_dt, const float* __restrict__ log_A_real,
    const float* __restrict__ A_imag, const float* __restrict__ Dsk, int l)
{
    const int h = blockIdx.x, b = blockIdx.y;
    const int tid = threadIdx.x;
    const int lane = tid & 63, wv = tid >> 6;
    __shared__ float2 wsh[32];
    __shared__ float dsh;
    __shared__ unsigned Ub[64][36];    // u bf16 pairs
    __shared__ unsigned Sb[64][36];    // state hi
    __shared__ unsigned Sc[64][36];    // state lo (residual)
    __shared__ float2 scr[64][33];     // A-agg, then Y

    if (tid < 32) {
        const size_t pidx = ((size_t)l * 256 + h) * 32 + tid;
        const float dt = __expf(log_dt[l * 256 + h]);
        const float Ar = -__expf(log_A_real[pidx]);
        const float Ai = A_imag[pidx];
        const float er = __expf(Ar * dt);
        float sv, cv;
        __sincosf(Ai * dt, &sv, &cv);
        wsh[tid] = make_float2(er * cv, er * sv);
    }
    if (tid == 32) dsh = Dsk[l * 256 + h];

    // ---- stage U: thread owns t = tid*8..+8 = chunk c0q, j0q..+8 ----
    const int c0q = tid >> 2, j0q = (tid & 3) * 8;
    {
        const float* zrp = z + ((size_t)b * 512 + h) * 2048 + tid * 8;
        const float* zip = zrp + 256 * 2048;
        const float4 r0 = *(const float4*)zrp, r1 = *(const float4*)(zrp + 4);
        const float4 i0 = *(const float4*)zip, i1 = *(const float4*)(zip + 4);
        uint4 pa, pb;
        pa.x = cvt_pk_bf16(r0.x, i0.x); pa.y = cvt_pk_bf16(r0.y, i0.y);
        pa.z = cvt_pk_bf16(r0.z, i0.z); pa.w = cvt_pk_bf16(r0.w, i0.w);
        pb.x = cvt_pk_bf16(r1.x, i1.x); pb.y = cvt_pk_bf16(r1.y, i1.y);
        pb.z = cvt_pk_bf16(r1.z, i1.z); pb.w = cvt_pk_bf16(r1.w, i1.w);
        *(uint4*)&Ub[c0q][j0q]     = pa;
        *(uint4*)&Ub[c0q][j0q + 4] = pb;
    }
    __syncthreads();

    const unsigned short* Pg = Pmat + (size_t)h * 12288;
    const unsigned short* Tg = Pg + 4096;
    const unsigned short* Mg = Pg + 8192;
    const int bcol = lane & 15, kq = (lane >> 4) * 8;
    const int arow = (wv * 16 + bcol) * 64 + kq;
    const float2 zero2 = make_float2(0.f, 0.f);

    // a2 = Y accumulator, carried in registers across the butterfly
    float4v a2[4];
#pragma unroll
    for (int jf = 0; jf < 4; ++jf) a2[jf] = (float4v){0.f, 0.f, 0.f, 0.f};

    // ---- phase 1: A-agg = P x U  AND  Ytri = TriG x U (shared bf reads) ----
    {
        float4v a1[4];
#pragma unroll
        for (int jf = 0; jf < 4; ++jf) a1[jf] = (float4v){0.f, 0.f, 0.f, 0.f};
#pragma unroll
        for (int k0 = 0; k0 < 64; k0 += 32) {
            const short8 afP = *(const short8*)(Pg + arow + k0);
            const short8 afT = *(const short8*)(Tg + arow + k0);
#pragma unroll
            for (int jf = 0; jf < 4; ++jf) {
                const short8 bf = *(const short8*)&Ub[16 * jf + bcol][(k0 + kq) >> 1];
                a1[jf] = __builtin_amdgcn_mfma_f32_16x16x32_bf16(afP, bf, a1[jf], 0, 0, 0);
                a2[jf] = __builtin_amdgcn_mfma_f32_16x16x32_bf16(afT, bf, a2[jf], 0, 0, 0);
            }
        }
        const int mode0 = (wv * 16 + (lane >> 4) * 4) >> 1;
#pragma unroll
        for (int jf = 0; jf < 4; ++jf) {
            const int c = 16 * jf + bcol;
            scr[c][mode0]     = make_float2(a1[jf][0], a1[jf][1]);
            scr[c][mode0 + 1] = make_float2(a1[jf][2], a1[jf][3]);
        }
    }
    __syncthreads();

    // ---- butterfly scan over 64 chunk-aggregates; wave wv owns 8 modes ----
    {
        const int dstc = (lane + 1) & 63;
#pragma unroll 1
        for (int jm = 0; jm < 8; ++jm) {
            const int n = wv * 8 + jm;
            const float2 wm = wsh[n];
            float2 f = wm;
#pragma unroll
            for (int s = 0; s < 5; ++s) f = cfma(f, f, zero2);   // w^32
            float2 qv = scr[lane][n], pq = f;
#pragma unroll
            for (int s = 0; s < 6; ++s) {
                const int d = 1 << s;
                float2 sh;
                sh.x = __shfl_up(qv.x, (unsigned)d);
                sh.y = __shfl_up(qv.y, (unsigned)d);
                const float2 qn = cfma(pq, sh, qv);
                if (lane >= d) qv = qn;
                pq = cfma(pq, pq, zero2);
            }
            // exclusive via store-to-lane+1; split hi/lo bf16
            const unsigned hi = cvt_pk_bf16(qv.x, qv.y);
            const float2 hv = unpk(hi);
            const unsigned lo = cvt_pk_bf16(qv.x - hv.x, qv.y - hv.y);
            Sb[dstc][n] = (lane == 63) ? 0u : hi;
            Sc[dstc][n] = (lane == 63) ? 0u : lo;
        }
    }
    __syncthreads();

    // ---- phase 2: Y += M x S_hi + M x S_lo; write Y -> scr ----
    {
#pragma unroll
        for (int k0 = 0; k0 < 64; k0 += 32) {
            const short8 afM = *(const short8*)(Mg + arow + k0);
#pragma unroll
            for (int jf = 0; jf < 4; ++jf) {
                const short8 bf = *(const short8*)&Sb[16 * jf + bcol][(k0 + kq) >> 1];
                a2[jf] = __builtin_amdgcn_mfma_f32_16x16x32_bf16(afM, bf, a2[jf], 0, 0, 0);
            }
        }
#pragma unroll
        for (int k0 = 0; k0 < 64; k0 += 32) {
            const short8 afM = *(const short8*)(Mg + arow + k0);
#pragma unroll
            for (int jf = 0; jf < 4; ++jf) {
                const short8 bf = *(const short8*)&Sc[16 * jf + bcol][(k0 + kq) >> 1];
                a2[jf] = __builtin_amdgcn_mfma_f32_16x16x32_bf16(afM, bf, a2[jf], 0, 0, 0);
            }
        }
        // scr's last reads were in the butterfly (covered by the sync above);
        // safe to overwrite with Y without an extra barrier.
        const int jp0 = (wv * 16 + (lane >> 4) * 4) >> 1;
#pragma unroll
        for (int jf = 0; jf < 4; ++jf) {
            const int c = 16 * jf + bcol;
            scr[c][jp0]     = make_float2(a2[jf][0], a2[jf][1]);
            scr[c][jp0 + 1] = make_float2(a2[jf][2], a2[jf][3]);
        }
    }
    __syncthreads();

    // ---- final: D-skip + gelu + bf16 pack + coalesced stores ----
    {
        const float dv = dsh;
        unsigned short* yrp = y + ((size_t)b * 512 + h) * 2048 + tid * 8;
        unsigned short* yip = yrp + 256 * 2048;
        short8 vr8, vi8;
#pragma unroll
        for (int j = 0; j < 8; ++j) {
            const float2 yv = scr[c0q][j0q + j];
            const float2 uv = unpk(Ub[c0q][j0q + j]);
            ((unsigned short*)&vr8)[j] = f2bf(gelu_tanh(__builtin_fmaf(dv, uv.x, yv.x)));
            ((unsigned short*)&vi8)[j] = f2bf(gelu_tanh(__builtin_fmaf(dv, uv.y, yv.y)));
        }
        *(short8*)yrp = vr8;
        *(short8*)yip = vi8;
    }
}

extern "C" void kernel_launch(void* const* d_in, const int* in_sizes, int n_in,
                              void* d_out, int out_size, void* d_ws, size_t ws_size,
                              hipStream_t stream)
{
    const float* x        = (const float*)d_in[0];
    const float* enc_Wr   = (const float*)d_in[1];
    const float* enc_Wi   = (const float*)d_in[2];
    const float* enc_br   = (const float*)d_in[3];
    const float* enc_bi   = (const float*)d_in[4];
    const float* log_dt   = (const float*)d_in[5];
    const float* log_A_r  = (const float*)d_in[6];
    const float* A_imag   = (const float*)d_in[7];
    const float* C_r      = (const float*)d_in[8];
    const float* C_i      = (const float*)d_in[9];
    const float* Dp       = (const float*)d_in[10];
    const float* out_Wr   = (const float*)d_in[11];
    const float* out_Wi   = (const float*)d_in[12];
    const float* out_br   = (const float*)d_in[13];
    const float* out_bi   = (const float*)d_in[14];
    const float* ln_gr    = (const float*)d_in[15];
    const float* ln_gi    = (const float*)d_in[16];
    const float* ln_br    = (const float*)d_in[17];
    const float* ln_bi    = (const float*)d_in[18];
    const float* dec_Wr   = (const float*)d_in[19];
    const float* dec_Wi   = (const float*)d_in[20];
    const float* dec_br   = (const float*)d_in[21];
    const float* dec_bi   = (const float*)d_in[22];

    // ---- workspace layout (bytes) ----
    uint8_t* W = (uint8_t*)d_ws;
    float* z             = (float*)W;                       // 33,554,432
    unsigned short* Pmat = (unsigned short*)(W + 33554432); // 256x3x4096x2 = 6,291,456 (rebuilt per layer)
    unsigned short* A_enc= (unsigned short*)(W + 50331648); // 512x1056x2  = 1,081,344
    unsigned short* A_lay= (unsigned short*)(W + 51412992); // 4x512x512x2 = 2,097,152
    unsigned short* A_dec= (unsigned short*)(W + 53510144); // 1152x512x2  = 1,179,648
    float* b_enc         = (float*)(W + 54689792);          // 512 f
    float* b_lay         = (float*)(W + 54691840);          // 2048 f
    float* b_dec         = (float*)(W + 54700032);          // 1028 f

    // ---- d_out doubles as scratch ----
    unsigned short* y   = (unsigned short*)((uint8_t*)d_out + 33554432);   // 16,777,216
    unsigned short* xp  = (unsigned short*)d_out;  // 34,603,008; dead after encoder GEMM

    // ---- build all weights/biases in one launch ----
    buildall_k<<<8527, 256, 0, stream>>>(enc_Wr, enc_Wi, out_Wr, out_Wi,
                                         dec_Wr, dec_Wi, enc_br, enc_bi,
                                         out_br, out_bi, dec_br, dec_bi,
                                         A_enc, A_lay, A_dec,
                                         b_enc, b_lay, b_dec);

    // ---- encoder: pack x -> xp, GEMM -> z ----
    packx_k<<<dim3(32, 9, 8), 256, 0, stream>>>(x, xp);
    mgemm_k<<<dim3(4, 16, 8), 256, 0, stream>>>(A_enc, b_enc, xp, z, 512, 1056);

    // ---- layers: scan-matrices -> MFMA scan -> fused GEMM+residual+LN ----
    for (int l = 0; l < 4; ++l) {
        buildmm_k<<<256, 256, 0, stream>>>(log_dt, log_A_r, A_imag, C_r, C_i, Pmat, l);
        s4mm_k<<<dim3(256, 8), 256, 0, stream>>>(z, y, Pmat, log_dt, log_A_r,
                                                 A_imag, Dp, l);
        mgemmln_k<<<dim3(32, 8), 512, 0, stream>>>(A_lay + (size_t)l * 262144,
                                                   b_lay + l * 512, y, z,
                                                   ln_gr, ln_gi, ln_br, ln_bi, l);
    }

    // ---- decoder: single-pass fused transpose+convert+GEMM -> d_out ----
    mgemmdec_k<<<dim3(32, 8), 512, 0, stream>>>(A_dec, b_dec, z, (float*)d_out);
}

// Round 17
// 507.769 us; speedup vs baseline: 1.0461x; 1.0300x over previous
//
#include <hip/hip_runtime.h>
#include <cstddef>
#include <cstdint>

// B=8, C=2, Hf=257, T=2048, D_IN=514, DM=256, NL=4, N=32
// Activations: fp32 planes (b, 2*DM=512, T). GEMMs run bf16 MFMA.
// R17: all 4 layers' scan matrices built in ONE launch (grid 256x4) before
// the layer loop, stored in d_out scratch [0, 25.2MB) (dead after the
// encoder GEMM consumes xp; decoder overwrites d_out only at the end).
// Removes the serial per-layer buildmm launch from the loop (15 -> 12
// launches). Kernel bodies otherwise identical to R16 (verified 523us).

typedef __attribute__((ext_vector_type(8))) short short8;
typedef __attribute__((ext_vector_type(4))) float float4v;

__device__ __forceinline__ unsigned short f2bf(float f) {
    union { float f; unsigned u; } v; v.f = f;
    const unsigned r = v.u + 0x7fffu + ((v.u >> 16) & 1u);  // RNE
    return (unsigned short)(r >> 16);
}

__device__ __forceinline__ float gelu_tanh(float x) {
    const float x3 = x * x * x;
    const float v  = 0.7978845608028654f * (x + 0.044715f * x3);
    const float e  = __expf(2.f * v);
    const float th = 1.f - 2.f / (e + 1.f);
    return 0.5f * x * (1.f + th);
}

// packed bf16 pair: dst.lo = bf16(lo), dst.hi = bf16(hi) (RNE)
__device__ __forceinline__ unsigned cvt_pk_bf16(float lo, float hi) {
    unsigned r;
    asm("v_cvt_pk_bf16_f32 %0, %1, %2" : "=v"(r) : "v"(lo), "v"(hi));
    return r;
}
// unpack bf16x2 dword -> float2 (exact)
__device__ __forceinline__ float2 unpk(unsigned d) {
    float2 u;
    u.x = __uint_as_float(d << 16);
    u.y = __uint_as_float(d & 0xffff0000u);
    return u;
}

// packed complex mul-add: w (*) p + u via 2x v_pk_fma_f32
__device__ __forceinline__ float2 cfma(const float2 w, const float2 p,
                                       const float2 u) {
    float2 t, r;
    asm("v_pk_fma_f32 %0, %1, %2, %3 op_sel:[1,1,0] op_sel_hi:[1,0,1] neg_lo:[1,0,0] neg_hi:[0,0,0]"
        : "=v"(t) : "v"(w), "v"(p), "v"(u));
    asm("v_pk_fma_f32 %0, %1, %2, %3 op_sel:[0,0,0] op_sel_hi:[0,1,1]"
        : "=v"(r) : "v"(w), "v"(p), "v"(t));
    return r;
}

#define ASYNC_COPY16(gp, lp) __builtin_amdgcn_global_load_lds( \
    (const __attribute__((address_space(1))) unsigned int*)(gp), \
    (__attribute__((address_space(3))) unsigned int*)(lp), 16, 0, 0)

// ---------- ONE builder launch for all weights/biases ----------
__global__ __launch_bounds__(256) void buildall_k(
    const float* __restrict__ enc_Wr, const float* __restrict__ enc_Wi,
    const float* __restrict__ out_Wr, const float* __restrict__ out_Wi,
    const float* __restrict__ dec_Wr, const float* __restrict__ dec_Wi,
    const float* __restrict__ enc_br, const float* __restrict__ enc_bi,
    const float* __restrict__ out_br, const float* __restrict__ out_bi,
    const float* __restrict__ dec_br, const float* __restrict__ dec_bi,
    unsigned short* __restrict__ A_enc, unsigned short* __restrict__ A_lay,
    unsigned short* __restrict__ A_dec,
    float* __restrict__ b_enc, float* __restrict__ b_lay,
    float* __restrict__ b_dec)
{
    int blk = blockIdx.x;
    const int tid = threadIdx.x;
    if (blk < 2112) {
        const int i = blk * 256 + tid;
        const int m = i / 1056, k = i - m * 1056;
        const int ri = m >= 256, g = m & 255;
        const int blk2 = k >= 528;
        const int hh = k - blk2 * 528;
        float val = 0.f;
        if (hh < 514) {
            const float wr = enc_Wr[(size_t)g * 514 + hh];
            const float wi = enc_Wi[(size_t)g * 514 + hh];
            val = ri ? (blk2 ? wr : wi) : (blk2 ? -wi : wr);
        }
        A_enc[i] = f2bf(val);
        return;
    }
    blk -= 2112;
    if (blk < 4096) {
        const int l = blk >> 10;
        const int i = ((blk & 1023) << 8) + tid;
        const float* Wr = out_Wr + (size_t)l * 65536;
        const float* Wi = out_Wi + (size_t)l * 65536;
        const int m = i >> 9, k = i & 511;
        const int ri = m >= 256, g = m & 255;
        const int blk2 = k >> 8, hh = k & 255;
        const float wr = Wr[(size_t)g * 256 + hh];
        const float wi = Wi[(size_t)g * 256 + hh];
        A_lay[(size_t)l * 262144 + i] =
            f2bf(ri ? (blk2 ? wr : wi) : (blk2 ? -wi : wr));
        return;
    }
    blk -= 4096;
    if (blk < 2304) {
        // decoder W, INTERLEAVED rows: m' -> (g = m'>>1, comp = m'&1).
        const int i = blk * 256 + tid;
        const int m = i >> 9, k = i & 511;
        const int g = m >> 1, comp = m & 1;
        float val = 0.f;
        if (g < 514) {
            const int blk2 = k >> 8, hh = k & 255;
            const float wr = dec_Wr[(size_t)g * 256 + hh];
            const float wi = dec_Wi[(size_t)g * 256 + hh];
            val = comp ? (blk2 ? wr : wi) : (blk2 ? -wi : wr);
        }
        A_dec[i] = f2bf(val);
        return;
    }
    blk -= 2304;
    if (blk < 2) {
        const int i = blk * 256 + tid;
        b_enc[i] = (i < 256) ? enc_br[i] : enc_bi[i - 256];
        return;
    }
    blk -= 2;
    if (blk < 8) {
        const int l = blk >> 1;
        const int i = ((blk & 1) << 8) + tid;
        b_lay[l * 512 + i] = (i < 256) ? out_br[l * 256 + i]
                                       : out_bi[l * 256 + i - 256];
        return;
    }
    blk -= 8;
    {
        const int i = blk * 256 + tid;
        if (i < 1028) b_dec[i] = (i & 1) ? dec_bi[i >> 1] : dec_br[i >> 1];
    }
}

// ---------- scan-matrix builder, ALL 4 layers: P / TriG / M per (l,h) ----------
// grid (256, 4): blockIdx.x = h, blockIdx.y = l. Pmat layout per (l,h):
// [l][h][3][64*64] bf16, rows/cols interleaved re/im:
// entry(2a+ri, 2b+ci) of complex coef v: ri=0:(Re,-Im) ri=1:(Im,Re).
__global__ __launch_bounds__(256) void buildmm_k(
    const float* __restrict__ log_dt, const float* __restrict__ log_A_real,
    const float* __restrict__ A_imag, const float* __restrict__ C_r,
    const float* __restrict__ C_i, unsigned short* __restrict__ Pmat)
{
    const int h = blockIdx.x, l = blockIdx.y;
    const int tid = threadIdx.x;
    __shared__ float2 pw[32][33];
    __shared__ float2 csh[32], gsh[32];

    if (tid < 32) {
        const size_t pidx = ((size_t)l * 256 + h) * 32 + tid;
        const float dt = __expf(log_dt[l * 256 + h]);
        const float Ar = -__expf(log_A_real[pidx]);
        const float Ai = A_imag[pidx];
        const float er = __expf(Ar * dt);
        float sv, cv;
        __sincosf(Ai * dt, &sv, &cv);
        const float wr = er * cv, wi = er * sv;
        const float den = 1.f / (Ar * Ar + Ai * Ai);
        const float nr = wr - 1.f, ni = wi;
        const float qr = (nr * Ar + ni * Ai) * den;
        const float qi = (ni * Ar - nr * Ai) * den;
        const float cr = C_r[pidx], ci = C_i[pidx];
        csh[tid] = make_float2(cr * qr - ci * qi, cr * qi + ci * qr);
        float2 p = make_float2(1.f, 0.f);
        const float2 w = make_float2(wr, wi);
#pragma unroll 1
        for (int k = 0; k < 33; ++k) {
            pw[tid][k] = p;
            const float pr = p.x * w.x - p.y * w.y;
            p.y = p.x * w.y + p.y * w.x;
            p.x = pr;
        }
    }
    __syncthreads();
    if (tid < 32) {
        float2 g = make_float2(0.f, 0.f);
#pragma unroll 1
        for (int n = 0; n < 32; ++n) {
            const float2 c = csh[n], p = pw[n][tid];
            g.x += c.x * p.x - c.y * p.y;
            g.y += c.x * p.y + c.y * p.x;
        }
        gsh[tid] = g;
    }
    __syncthreads();

    unsigned short* base = Pmat + ((size_t)l * 256 + h) * 12288;
    const int row = tid >> 2, cq = (tid & 3) * 16;
    const int half = row & 1, src = row >> 1;
#pragma unroll 1
    for (int c = cq; c < cq + 16; ++c) {
        const int ci = c & 1, idx = c >> 1;
        const float2 v = pw[src][31 - idx];
        base[row * 64 + c] = f2bf(half ? (ci ? v.x : v.y) : (ci ? -v.y : v.x));
        const float2 g = (idx <= src) ? gsh[src - idx] : make_float2(0.f, 0.f);
        base[4096 + row * 64 + c] = f2bf(half ? (ci ? g.x : g.y) : (ci ? -g.y : g.x));
        const float2 wp = pw[idx][src + 1];
        const float2 cc = csh[idx];
        const float2 e = make_float2(cc.x * wp.x - cc.y * wp.y,
                                     cc.x * wp.y + cc.y * wp.x);
        base[8192 + row * 64 + c] = f2bf(half ? (ci ? e.x : e.y) : (ci ? -e.y : e.x));
    }
}

// ---------- encoder input pack: x (b,514,T,2) fp32 -> xp (b,T,1056) bf16 ----------
__global__ __launch_bounds__(256) void packx_k(const float* __restrict__ x,
                                               unsigned short* __restrict__ xp)
{
    const int t0 = blockIdx.x * 64, d0 = blockIdx.y * 64, b = blockIdx.z;
    __shared__ unsigned short tr_[64][72];
    __shared__ unsigned short ti_[64][72];
    const int tid = threadIdx.x;
    const int tp = tid & 31, dl0 = tid >> 5;
#pragma unroll
    for (int p = 0; p < 8; ++p) {
        const int d = dl0 + p * 8;
        const int gd = d0 + d;
        float4 v = make_float4(0.f, 0.f, 0.f, 0.f);
        if (gd < 514) v = *(const float4*)(x + (((size_t)b * 514 + gd) * 2048 + t0 + tp * 2) * 2);
        tr_[tp * 2 + 0][d] = f2bf(v.x); ti_[tp * 2 + 0][d] = f2bf(v.y);
        tr_[tp * 2 + 1][d] = f2bf(v.z); ti_[tp * 2 + 1][d] = f2bf(v.w);
    }
    __syncthreads();
    const int dc = tid & 7;
    const int kloc = d0 + dc * 8;
    if (kloc < 528) {
#pragma unroll
        for (int p = 0; p < 2; ++p) {
            const int t = (tid >> 3) + p * 32;
            const size_t rowb = ((size_t)b * 2048 + t0 + t) * 1056;
            *(short8*)&xp[rowb + kloc]       = *(const short8*)&tr_[t][dc * 8];
            *(short8*)&xp[rowb + 528 + kloc] = *(const short8*)&ti_[t][dc * 8];
        }
    }
}

// ---------- bf16 MFMA GEMM (encoder): out(b,M,T) = A * Bm^T + bias ----------
__global__ __launch_bounds__(256, 2) void mgemm_k(
    const unsigned short* __restrict__ A, const float* __restrict__ bias,
    const unsigned short* __restrict__ Bm, float* __restrict__ out,
    int M, int Kp)
{
    __shared__ unsigned short As[4096];  // [m 0..127][k 0..31]
    __shared__ unsigned short Bs[4096];  // [t 0..127][k 0..31]
    const int tid = threadIdx.x;
    const int w = tid >> 6, lane = tid & 63;
    const int m0 = blockIdx.x * 128, t0 = blockIdx.y * 128, b = blockIdx.z;
    const int wm = w & 1, wn = w >> 1;

    const unsigned short* Ab = A + (size_t)m0 * Kp;
    const unsigned short* Bb = Bm + ((size_t)b * 2048 + t0) * Kp;

    const int c0 = w * 64 + lane;
    const int r0 = c0 >> 2, q0 = (c0 & 3) * 8;
    const int c1 = c0 + 256;
    const int r1 = c1 >> 2, q1 = (c1 & 3) * 8;
    unsigned short* As0 = &As[(size_t)(w * 64) * 8];
    unsigned short* As1 = &As[(size_t)(w * 64 + 256) * 8];
    unsigned short* Bs0 = &Bs[(size_t)(w * 64) * 8];
    unsigned short* Bs1 = &Bs[(size_t)(w * 64 + 256) * 8];

    float4v acc[4][4];
#pragma unroll
    for (int i = 0; i < 4; ++i)
#pragma unroll
        for (int j = 0; j < 4; ++j) acc[i][j] = (float4v){0.f, 0.f, 0.f, 0.f};

    const int arow = wm * 64 + (lane & 15);
    const int brow = wn * 64 + (lane & 15);
    const int kq = (lane >> 4) * 8;

    for (int k0 = 0; k0 < Kp; k0 += 32) {
        ASYNC_COPY16(Ab + (size_t)r0 * Kp + k0 + q0, As0);
        ASYNC_COPY16(Ab + (size_t)r1 * Kp + k0 + q1, As1);
        ASYNC_COPY16(Bb + (size_t)r0 * Kp + k0 + q0, Bs0);
        ASYNC_COPY16(Bb + (size_t)r1 * Kp + k0 + q1, Bs1);
        __syncthreads();
        short8 af[4], bf[4];
#pragma unroll
        for (int i = 0; i < 4; ++i) af[i] = *(const short8*)&As[(arow + i * 16) * 32 + kq];
#pragma unroll
        for (int j = 0; j < 4; ++j) bf[j] = *(const short8*)&Bs[(brow + j * 16) * 32 + kq];
#pragma unroll
        for (int i = 0; i < 4; ++i)
#pragma unroll
            for (int j = 0; j < 4; ++j)
                acc[i][j] = __builtin_amdgcn_mfma_f32_16x16x32_bf16(af[i], bf[j], acc[i][j], 0, 0, 0);
        __syncthreads();
    }

    const int col = lane & 15;
    const int rq = (lane >> 4) * 4;
#pragma unroll
    for (int i = 0; i < 4; ++i) {
        const int mloc = wm * 64 + i * 16 + rq;
#pragma unroll
        for (int r = 0; r < 4; ++r) {
            const int m = m0 + mloc + r;
            const float bs = bias[m];
#pragma unroll
            for (int j = 0; j < 4; ++j) {
                const int t = t0 + wn * 64 + j * 16 + col;
                out[((size_t)b * 512 + m) * 2048 + t] = acc[i][j][r] + bs;
            }
        }
    }
}

// ---------- fused layer GEMM + residual + channel LayerNorm ----------
// R7 verified optimum: 64-t tile, B staged directly from t-major y planes
// (transpose on the LDS write), XOR swizzle mask(t) = ((t&7)^((t>>3)&7))<<4.
__global__ __launch_bounds__(512, 2) void mgemmln_k(
    const unsigned short* __restrict__ A, const float* __restrict__ bias,
    const unsigned short* __restrict__ Bm, float* __restrict__ z,
    const float* __restrict__ gamr, const float* __restrict__ gami,
    const float* __restrict__ betr, const float* __restrict__ beti, int l)
{
    __shared__ unsigned short Bs[64][512];   // 64KB, swizzled
    __shared__ float biasS[512], gamS[512], betS[512];
    __shared__ float sred[8][64][2];
    __shared__ float sstat[2][64][2];
    const int tid = threadIdx.x;
    const int w = tid >> 6, lane = tid & 63;
    const int t0g = blockIdx.x * 64, b = blockIdx.y;
    unsigned char* BsB = (unsigned char*)&Bs[0][0];

    // ---- stage B from y planes, transpose-on-write ----
    {
        const unsigned short* ysrc = Bm + (size_t)b * 512 * 2048 + t0g;
        const int tseg = lane & 7;       // 8-t segment (t = tseg*8 + j)
        const int rloc = lane >> 3;      // row within the wave's octet
#pragma unroll
        for (int p = 0; p < 8; ++p) {
            const int krow = w * 8 + rloc + p * 64;
            const short8 v = *(const short8*)(ysrc + (size_t)krow * 2048 + tseg * 8);
#pragma unroll
            for (int j = 0; j < 8; ++j) {
                const int t = tseg * 8 + j;
                const int mask = (((t & 7) ^ ((t >> 3) & 7)) << 4);
                *(unsigned short*)(BsB + t * 1024 + ((krow * 2) ^ mask)) =
                    ((const unsigned short*)&v)[j];
            }
        }
        const int m = tid, g = m & 255, comp = m >> 8;
        biasS[m] = bias[m];
        gamS[m] = (comp ? gami : gamr)[l * 256 + g];
        betS[m] = (comp ? beti : betr)[l * 256 + g];
    }
    __syncthreads();

    // ---- K-loop: A direct from global (L2-resident), B from LDS ----
    float4v acc[4][4];
#pragma unroll
    for (int i = 0; i < 4; ++i)
#pragma unroll
        for (int j = 0; j < 4; ++j) acc[i][j] = (float4v){0.f, 0.f, 0.f, 0.f};

    const int brow = lane & 15;
    const int kq8 = (lane >> 4) * 8;
    const unsigned short* Ab = A + ((size_t)(w * 64 + brow)) * 512 + kq8;
    int baseB[4], maskB[4];
#pragma unroll
    for (int j = 0; j < 4; ++j) {
        const int t = j * 16 + brow;
        baseB[j] = t * 1024;
        maskB[j] = (((t & 7) ^ ((t >> 3) & 7)) << 4);
    }

#define LOADF(af_, bf_, k0_) do {                                              \
    _Pragma("unroll")                                                          \
    for (int i = 0; i < 4; ++i)                                                \
        af_[i] = *(const short8*)(Ab + (size_t)i * 16 * 512 + (k0_));          \
    _Pragma("unroll")                                                          \
    for (int j = 0; j < 4; ++j)                                                \
        bf_[j] = *(const short8*)(BsB + baseB[j] + ((((k0_) + kq8) * 2) ^ maskB[j])); \
} while (0)
#define MFMAS(af_, bf_) do {                                                   \
    _Pragma("unroll")                                                          \
    for (int i = 0; i < 4; ++i)                                                \
        _Pragma("unroll")                                                      \
        for (int j = 0; j < 4; ++j)                                            \
            acc[i][j] = __builtin_amdgcn_mfma_f32_16x16x32_bf16(af_[i], bf_[j], acc[i][j], 0, 0, 0); \
} while (0)

    {
        short8 afA[4], bfA[4], afB[4], bfB[4];
        LOADF(afA, bfA, 0);
#pragma unroll 1
        for (int kk = 0; kk < 16; kk += 2) {
            LOADF(afB, bfB, kk * 32 + 32);
            MFMAS(afA, bfA);
            if (kk + 2 < 16) LOADF(afA, bfA, kk * 32 + 64);
            MFMAS(afB, bfB);
        }
    }
#undef LOADF
#undef MFMAS

    // ---- epilogue: v = acc + bias + z_old, LN stats, normalize, write z ----
    const int q4 = (lane >> 4) * 4;
    float4 b4[4], g4[4], e4[4];
#pragma unroll
    for (int i = 0; i < 4; ++i) {
        const int m0 = w * 64 + i * 16 + q4;
        b4[i] = *(const float4*)&biasS[m0];
        g4[i] = *(const float4*)&gamS[m0];
        e4[i] = *(const float4*)&betS[m0];
    }

    float s1[4], s2[4];
#pragma unroll
    for (int j = 0; j < 4; ++j) { s1[j] = 0.f; s2[j] = 0.f; }
#pragma unroll
    for (int j = 0; j < 4; ++j) {
        const int t = t0g + j * 16 + brow;
#pragma unroll
        for (int i = 0; i < 4; ++i) {
            const int m = w * 64 + i * 16 + q4;
            const float* zp = &z[((size_t)b * 512 + m) * 2048 + t];
            const float bb[4] = {b4[i].x, b4[i].y, b4[i].z, b4[i].w};
#pragma unroll
            for (int r = 0; r < 4; ++r) {
                const float v = acc[i][j][r] + bb[r] + zp[(size_t)r * 2048];
                acc[i][j][r] = v;
                s1[j] += v; s2[j] += v * v;
            }
        }
    }
#pragma unroll
    for (int j = 0; j < 4; ++j) {
        s1[j] += __shfl_xor(s1[j], 16); s2[j] += __shfl_xor(s2[j], 16);
        s1[j] += __shfl_xor(s1[j], 32); s2[j] += __shfl_xor(s2[j], 32);
    }
    if (lane < 16) {
#pragma unroll
        for (int j = 0; j < 4; ++j) {
            sred[w][j * 16 + lane][0] = s1[j];
            sred[w][j * 16 + lane][1] = s2[j];
        }
    }
    __syncthreads();
    if (tid < 128) {
        const int t = tid & 63, comp = tid >> 6;
        float S1 = 0.f, S2 = 0.f;
#pragma unroll
        for (int w2 = 0; w2 < 4; ++w2) {
            S1 += sred[comp * 4 + w2][t][0];
            S2 += sred[comp * 4 + w2][t][1];
        }
        const float mn = S1 * (1.f / 256.f);
        const float var = S2 * (1.f / 256.f) - mn * mn;
        sstat[comp][t][0] = mn;
        sstat[comp][t][1] = rsqrtf(var + 1e-5f);
    }
    __syncthreads();
    const int comp = w >> 2;
#pragma unroll
    for (int j = 0; j < 4; ++j) {
        const int tl = j * 16 + brow;
        const float mn = sstat[comp][tl][0], rs = sstat[comp][tl][1];
        const int t = t0g + tl;
#pragma unroll
        for (int i = 0; i < 4; ++i) {
            const int m = w * 64 + i * 16 + q4;
            float* zp = &z[((size_t)b * 512 + m) * 2048 + t];
            const float gg[4] = {g4[i].x, g4[i].y, g4[i].z, g4[i].w};
            const float ee[4] = {e4[i].x, e4[i].y, e4[i].z, e4[i].w};
#pragma unroll
            for (int r = 0; r < 4; ++r)
                zp[(size_t)r * 2048] = (acc[i][j][r] - mn) * rs * gg[r] + ee[r];
        }
    }
}

// ---------- fused decoder: transpose+convert z in-stage, GEMM, paired out ----------
// R13 (verified): ONE block per (t-tile, b); outer loop over 3 m-chunks of
// 384 rows; z staged once. A rows interleaved (m' -> g=m'>>1, comp=m'&1)
// -> float2 {re,im} full-line stores (R7).
__global__ __launch_bounds__(512, 1) void mgemmdec_k(
    const unsigned short* __restrict__ A, const float* __restrict__ bias,
    const float* __restrict__ z, float* __restrict__ out)
{
    __shared__ unsigned short Bs[64][512];   // 64KB, swizzled
    const int tid = threadIdx.x;
    const int w = tid >> 6, lane = tid & 63;
    const int t0g = blockIdx.x * 64, b = blockIdx.y;
    unsigned char* BsB = (unsigned char*)&Bs[0][0];

    // ---- stage B from z fp32 planes: f2bf + transpose-on-write (ONCE) ----
    {
        const float* zsrc = z + (size_t)b * 512 * 2048 + t0g;
        const int tseg = lane & 7, rloc = lane >> 3;
#pragma unroll
        for (int p = 0; p < 8; ++p) {
            const int krow = w * 8 + rloc + p * 64;
            const float* rowp = zsrc + (size_t)krow * 2048 + tseg * 8;
            const float4 va = *(const float4*)rowp;
            const float4 vb = *(const float4*)(rowp + 4);
            const float vals[8] = {va.x, va.y, va.z, va.w, vb.x, vb.y, vb.z, vb.w};
#pragma unroll
            for (int j = 0; j < 8; ++j) {
                const int t = tseg * 8 + j;
                const int mask = (((t & 7) ^ ((t >> 3) & 7)) << 4);
                *(unsigned short*)(BsB + t * 1024 + ((krow * 2) ^ mask)) = f2bf(vals[j]);
            }
        }
    }
    __syncthreads();

    const int brow = lane & 15;
    const int kq8 = (lane >> 4) * 8;
    int baseB[4], maskB[4];
#pragma unroll
    for (int j = 0; j < 4; ++j) {
        const int t = j * 16 + brow;
        baseB[j] = t * 1024;
        maskB[j] = (((t & 7) ^ ((t >> 3) & 7)) << 4);
    }

#define LOADF(af_, bf_, k0_) do {                                              \
    _Pragma("unroll")                                                          \
    for (int i = 0; i < 3; ++i)                                                \
        af_[i] = *(const short8*)(Ab + (size_t)i * 16 * 512 + (k0_));          \
    _Pragma("unroll")                                                          \
    for (int j = 0; j < 4; ++j)                                                \
        bf_[j] = *(const short8*)(BsB + baseB[j] + ((((k0_) + kq8) * 2) ^ maskB[j])); \
} while (0)
#define MFMAS(af_, bf_) do {                                                   \
    _Pragma("unroll")                                                          \
    for (int i = 0; i < 3; ++i)                                                \
        _Pragma("unroll")                                                      \
        for (int j = 0; j < 4; ++j)                                            \
            acc[i][j] = __builtin_amdgcn_mfma_f32_16x16x32_bf16(af_[i], bf_[j], acc[i][j], 0, 0, 0); \
} while (0)

#pragma unroll 1
    for (int mc = 0; mc < 3; ++mc) {
        const int m0b = mc * 384;
        const unsigned short* Ab = A + ((size_t)(m0b + w * 48 + brow)) * 512 + kq8;

        float4v acc[3][4];
#pragma unroll
        for (int i = 0; i < 3; ++i)
#pragma unroll
            for (int j = 0; j < 4; ++j) acc[i][j] = (float4v){0.f, 0.f, 0.f, 0.f};

        {
            short8 afA[3], bfA[4], afB[3], bfB[4];
            LOADF(afA, bfA, 0);
#pragma unroll 1
            for (int kk = 0; kk < 16; kk += 2) {
                LOADF(afB, bfB, kk * 32 + 32);
                MFMAS(afA, bfA);
                if (kk + 2 < 16) LOADF(afA, bfA, kk * 32 + 64);
                MFMAS(afB, bfB);
            }
        }

        // ---- epilogue: bias + paired float2 stores (g<514 guard) ----
        const int q4 = (lane >> 4) * 4;
#pragma unroll
        for (int i = 0; i < 3; ++i) {
            const int mb = m0b + w * 48 + i * 16 + q4;   // even
#pragma unroll
            for (int pr = 0; pr < 2; ++pr) {
                const int m2 = mb + pr * 2;              // even row of the pair
                const int g = m2 >> 1;
                if (g >= 514) continue;
                const float br = bias[m2], bi2 = bias[m2 + 1];
                float* op = out + (((size_t)b * 514 + g) * 2048 + t0g) * 2;
#pragma unroll
                for (int j = 0; j < 4; ++j) {
                    const int tl = j * 16 + brow;
                    const float2 v = make_float2(acc[i][j][pr * 2 + 0] + br,
                                                 acc[i][j][pr * 2 + 1] + bi2);
                    *(float2*)(op + (size_t)tl * 2) = v;
                }
            }
        }
    }
#undef LOADF
#undef MFMAS
}

// ---------- MFMA S4D scan: {A-agg,Ytri}={P,TriG}xU, butterfly, Y+=MxS ----------
// R16 (verified): TriG x U in phase 1 (shared Ub fragment loads with P x U),
// Y accumulator carried in registers across the butterfly; 4 barriers.
__global__ __launch_bounds__(256) void s4mm_k(
    const float* __restrict__ z, unsigned short* __restrict__ y,
    const unsigned short* __restrict__ Pmat,
    const float* __restrict__ log_dt, const float* __restrict__ log_A_real,
    const float* __restrict__ A_imag, const float* __restrict__ Dsk, int l)
{
    const int h = blockIdx.x, b = blockIdx.y;
    const int tid = threadIdx.x;
    const int lane = tid & 63, wv = tid >> 6;
    __shared__ float2 wsh[32];
    __shared__ float dsh;
    __shared__ unsigned Ub[64][36];    // u bf16 pairs
    __shared__ unsigned Sb[64][36];    // state hi
    __shared__ unsigned Sc[64][36];    // state lo (residual)
    __shared__ float2 scr[64][33];     // A-agg, then Y

    if (tid < 32) {
        const size_t pidx = ((size_t)l * 256 + h) * 32 + tid;
        const float dt = __expf(log_dt[l * 256 + h]);
        const float Ar = -__expf(log_A_real[pidx]);
        const float Ai = A_imag[pidx];
        const float er = __expf(Ar * dt);
        float sv, cv;
        __sincosf(Ai * dt, &sv, &cv);
        wsh[tid] = make_float2(er * cv, er * sv);
    }
    if (tid == 32) dsh = Dsk[l * 256 + h];

    // ---- stage U: thread owns t = tid*8..+8 = chunk c0q, j0q..+8 ----
    const int c0q = tid >> 2, j0q = (tid & 3) * 8;
    {
        const float* zrp = z + ((size_t)b * 512 + h) * 2048 + tid * 8;
        const float* zip = zrp + 256 * 2048;
        const float4 r0 = *(const float4*)zrp, r1 = *(const float4*)(zrp + 4);
        const float4 i0 = *(const float4*)zip, i1 = *(const float4*)(zip + 4);
        uint4 pa, pb;
        pa.x = cvt_pk_bf16(r0.x, i0.x); pa.y = cvt_pk_bf16(r0.y, i0.y);
        pa.z = cvt_pk_bf16(r0.z, i0.z); pa.w = cvt_pk_bf16(r0.w, i0.w);
        pb.x = cvt_pk_bf16(r1.x, i1.x); pb.y = cvt_pk_bf16(r1.y, i1.y);
        pb.z = cvt_pk_bf16(r1.z, i1.z); pb.w = cvt_pk_bf16(r1.w, i1.w);
        *(uint4*)&Ub[c0q][j0q]     = pa;
        *(uint4*)&Ub[c0q][j0q + 4] = pb;
    }
    __syncthreads();

    const unsigned short* Pg = Pmat + (size_t)h * 12288;
    const unsigned short* Tg = Pg + 4096;
    const unsigned short* Mg = Pg + 8192;
    const int bcol = lane & 15, kq = (lane >> 4) * 8;
    const int arow = (wv * 16 + bcol) * 64 + kq;
    const float2 zero2 = make_float2(0.f, 0.f);

    // a2 = Y accumulator, carried in registers across the butterfly
    float4v a2[4];
#pragma unroll
    for (int jf = 0; jf < 4; ++jf) a2[jf] = (float4v){0.f, 0.f, 0.f, 0.f};

    // ---- phase 1: A-agg = P x U  AND  Ytri = TriG x U (shared bf reads) ----
    {
        float4v a1[4];
#pragma unroll
        for (int jf = 0; jf < 4; ++jf) a1[jf] = (float4v){0.f, 0.f, 0.f, 0.f};
#pragma unroll
        for (int k0 = 0; k0 < 64; k0 += 32) {
            const short8 afP = *(const short8*)(Pg + arow + k0);
            const short8 afT = *(const short8*)(Tg + arow + k0);
#pragma unroll
            for (int jf = 0; jf < 4; ++jf) {
                const short8 bf = *(const short8*)&Ub[16 * jf + bcol][(k0 + kq) >> 1];
                a1[jf] = __builtin_amdgcn_mfma_f32_16x16x32_bf16(afP, bf, a1[jf], 0, 0, 0);
                a2[jf] = __builtin_amdgcn_mfma_f32_16x16x32_bf16(afT, bf, a2[jf], 0, 0, 0);
            }
        }
        const int mode0 = (wv * 16 + (lane >> 4) * 4) >> 1;
#pragma unroll
        for (int jf = 0; jf < 4; ++jf) {
            const int c = 16 * jf + bcol;
            scr[c][mode0]     = make_float2(a1[jf][0], a1[jf][1]);
            scr[c][mode0 + 1] = make_float2(a1[jf][2], a1[jf][3]);
        }
    }
    __syncthreads();

    // ---- butterfly scan over 64 chunk-aggregates; wave wv owns 8 modes ----
    {
        const int dstc = (lane + 1) & 63;
#pragma unroll 1
        for (int jm = 0; jm < 8; ++jm) {
            const int n = wv * 8 + jm;
            const float2 wm = wsh[n];
            float2 f = wm;
#pragma unroll
            for (int s = 0; s < 5; ++s) f = cfma(f, f, zero2);   // w^32
            float2 qv = scr[lane][n], pq = f;
#pragma unroll
            for (int s = 0; s < 6; ++s) {
                const int d = 1 << s;
                float2 sh;
                sh.x = __shfl_up(qv.x, (unsigned)d);
                sh.y = __shfl_up(qv.y, (unsigned)d);
                const float2 qn = cfma(pq, sh, qv);
                if (lane >= d) qv = qn;
                pq = cfma(pq, pq, zero2);
            }
            // exclusive via store-to-lane+1; split hi/lo bf16
            const unsigned hi = cvt_pk_bf16(qv.x, qv.y);
            const float2 hv = unpk(hi);
            const unsigned lo = cvt_pk_bf16(qv.x - hv.x, qv.y - hv.y);
            Sb[dstc][n] = (lane == 63) ? 0u : hi;
            Sc[dstc][n] = (lane == 63) ? 0u : lo;
        }
    }
    __syncthreads();

    // ---- phase 2: Y += M x S_hi + M x S_lo; write Y -> scr ----
    {
#pragma unroll
        for (int k0 = 0; k0 < 64; k0 += 32) {
            const short8 afM = *(const short8*)(Mg + arow + k0);
#pragma unroll
            for (int jf = 0; jf < 4; ++jf) {
                const short8 bf = *(const short8*)&Sb[16 * jf + bcol][(k0 + kq) >> 1];
                a2[jf] = __builtin_amdgcn_mfma_f32_16x16x32_bf16(afM, bf, a2[jf], 0, 0, 0);
            }
        }
#pragma unroll
        for (int k0 = 0; k0 < 64; k0 += 32) {
            const short8 afM = *(const short8*)(Mg + arow + k0);
#pragma unroll
            for (int jf = 0; jf < 4; ++jf) {
                const short8 bf = *(const short8*)&Sc[16 * jf + bcol][(k0 + kq) >> 1];
                a2[jf] = __builtin_amdgcn_mfma_f32_16x16x32_bf16(afM, bf, a2[jf], 0, 0, 0);
            }
        }
        // scr's last reads were in the butterfly (covered by the sync above);
        // safe to overwrite with Y without an extra barrier.
        const int jp0 = (wv * 16 + (lane >> 4) * 4) >> 1;
#pragma unroll
        for (int jf = 0; jf < 4; ++jf) {
            const int c = 16 * jf + bcol;
            scr[c][jp0]     = make_float2(a2[jf][0], a2[jf][1]);
            scr[c][jp0 + 1] = make_float2(a2[jf][2], a2[jf][3]);
        }
    }
    __syncthreads();

    // ---- final: D-skip + gelu + bf16 pack + coalesced stores ----
    {
        const float dv = dsh;
        unsigned short* yrp = y + ((size_t)b * 512 + h) * 2048 + tid * 8;
        unsigned short* yip = yrp + 256 * 2048;
        short8 vr8, vi8;
#pragma unroll
        for (int j = 0; j < 8; ++j) {
            const float2 yv = scr[c0q][j0q + j];
            const float2 uv = unpk(Ub[c0q][j0q + j]);
            ((unsigned short*)&vr8)[j] = f2bf(gelu_tanh(__builtin_fmaf(dv, uv.x, yv.x)));
            ((unsigned short*)&vi8)[j] = f2bf(gelu_tanh(__builtin_fmaf(dv, uv.y, yv.y)));
        }
        *(short8*)yrp = vr8;
        *(short8*)yip = vi8;
    }
}

extern "C" void kernel_launch(void* const* d_in, const int* in_sizes, int n_in,
                              void* d_out, int out_size, void* d_ws, size_t ws_size,
                              hipStream_t stream)
{
    const float* x        = (const float*)d_in[0];
    const float* enc_Wr   = (const float*)d_in[1];
    const float* enc_Wi   = (const float*)d_in[2];
    const float* enc_br   = (const float*)d_in[3];
    const float* enc_bi   = (const float*)d_in[4];
    const float* log_dt   = (const float*)d_in[5];
    const float* log_A_r  = (const float*)d_in[6];
    const float* A_imag   = (const float*)d_in[7];
    const float* C_r      = (const float*)d_in[8];
    const float* C_i      = (const float*)d_in[9];
    const float* Dp       = (const float*)d_in[10];
    const float* out_Wr   = (const float*)d_in[11];
    const float* out_Wi   = (const float*)d_in[12];
    const float* out_br   = (const float*)d_in[13];
    const float* out_bi   = (const float*)d_in[14];
    const float* ln_gr    = (const float*)d_in[15];
    const float* ln_gi    = (const float*)d_in[16];
    const float* ln_br    = (const float*)d_in[17];
    const float* ln_bi    = (const float*)d_in[18];
    const float* dec_Wr   = (const float*)d_in[19];
    const float* dec_Wi   = (const float*)d_in[20];
    const float* dec_br   = (const float*)d_in[21];
    const float* dec_bi   = (const float*)d_in[22];

    // ---- workspace layout (bytes) ----
    uint8_t* W = (uint8_t*)d_ws;
    float* z             = (float*)W;                       // 33,554,432
    unsigned short* A_enc= (unsigned short*)(W + 50331648); // 512x1056x2  = 1,081,344
    unsigned short* A_lay= (unsigned short*)(W + 51412992); // 4x512x512x2 = 2,097,152
    unsigned short* A_dec= (unsigned short*)(W + 53510144); // 1152x512x2  = 1,179,648
    float* b_enc         = (float*)(W + 54689792);          // 512 f
    float* b_lay         = (float*)(W + 54691840);          // 2048 f
    float* b_dec         = (float*)(W + 54700032);          // 1028 f

    // ---- d_out doubles as scratch ----
    unsigned short* y    = (unsigned short*)((uint8_t*)d_out + 33554432);  // 16,777,216
    unsigned short* xp   = (unsigned short*)d_out;  // 34,603,008; dead after encoder GEMM
    unsigned short* Pmat4= (unsigned short*)d_out;  // 4x6,291,456 = 25,165,824; lives
                                                    // AFTER encoder GEMM, dead at decoder

    // ---- build all weights/biases in one launch ----
    buildall_k<<<8527, 256, 0, stream>>>(enc_Wr, enc_Wi, out_Wr, out_Wi,
                                         dec_Wr, dec_Wi, enc_br, enc_bi,
                                         out_br, out_bi, dec_br, dec_bi,
                                         A_enc, A_lay, A_dec,
                                         b_enc, b_lay, b_dec);

    // ---- encoder: pack x -> xp, GEMM -> z ----
    packx_k<<<dim3(32, 9, 8), 256, 0, stream>>>(x, xp);
    mgemm_k<<<dim3(4, 16, 8), 256, 0, stream>>>(A_enc, b_enc, xp, z, 512, 1056);

    // ---- all-layer scan matrices (xp now dead; Pmat4 takes its place) ----
    buildmm_k<<<dim3(256, 4), 256, 0, stream>>>(log_dt, log_A_r, A_imag,
                                                C_r, C_i, Pmat4);

    // ---- layers: MFMA scan -> fused GEMM+residual+LN ----
    for (int l = 0; l < 4; ++l) {
        s4mm_k<<<dim3(256, 8), 256, 0, stream>>>(z, y, Pmat4 + (size_t)l * 3145728,
                                                 log_dt, log_A_r, A_imag, Dp, l);
        mgemmln_k<<<dim3(32, 8), 512, 0, stream>>>(A_lay + (size_t)l * 262144,
                                                   b_lay + l * 512, y, z,
                                                   ln_gr, ln_gi, ln_br, ln_bi, l);
    }

    // ---- decoder: single-pass fused transpose+convert+GEMM -> d_out ----
    mgemmdec_k<<<dim3(32, 8), 512, 0, stream>>>(A_dec, b_dec, z, (float*)d_out);
}